// Round 1
// baseline (2525.788 us; speedup 1.0000x reference)
//
#include <hip/hip_runtime.h>
#include <stdint.h>

typedef unsigned int u32;
typedef unsigned long long u64;
typedef unsigned char u8;

#define TSTEPS 8
#define BATCH 128
#define CH 128
#define NPIX1 784   // 28*28
#define NPIX2 196   // 14*14
#define TB 1024     // TSTEPS*BATCH
#define FC1_OUT 2048
#define FC1_IN 6272 // 128*49
#define FC2_OUT 10

// ---------------------------------------------------------------------------
// K1: conv1(1->128,3x3,SAME) + bn1 + IF over T=8 (constant input) + 2x2 maxpool
// output: p1bits[t][b][ci][8 u32]  (bit p = pooled spike at 14x14 pixel p)
// ---------------------------------------------------------------------------
__global__ __launch_bounds__(256) void k1_conv1_if_pool(
    const float* __restrict__ x, const float* __restrict__ w1,
    const float* __restrict__ g1, const float* __restrict__ b1,
    const float* __restrict__ m1, const float* __restrict__ v1,
    u32* __restrict__ p1bits)
{
    int blk = blockIdx.x;
    int b  = blk >> 7;
    int co = blk & 127;
    int tid = threadIdx.x;

    __shared__ u32 sbyte[NPIX1];

    double wk[9];
#pragma unroll
    for (int k = 0; k < 9; ++k) wk[k] = (double)w1[co * 9 + k];
    double inv  = (double)g1[co] / sqrt((double)v1[co] + 1e-5);
    double beta = (double)b1[co] - (double)m1[co] * inv;

    const float* xb = x + (size_t)b * NPIX1;

    for (int p = tid; p < NPIX1; p += 256) {
        int y  = p / 28;
        int xx = p - y * 28;
        double acc = 0.0;
#pragma unroll
        for (int dy = 0; dy < 3; ++dy) {
            int iy = y + dy - 1;
#pragma unroll
            for (int dx = 0; dx < 3; ++dx) {
                int ix = xx + dx - 1;
                if (iy >= 0 && iy < 28 && ix >= 0 && ix < 28)
                    acc += (double)xb[iy * 28 + ix] * wk[dy * 3 + dx];
            }
        }
        double yv = acc * inv + beta;
        double v = 0.0; u32 byte = 0;
#pragma unroll
        for (int t = 0; t < 8; ++t) {
            double h = v + yv;
            int s = (h >= 1.0);
            byte |= (u32)s << t;
            v = s ? 0.0 : h;
        }
        sbyte[p] = byte;
    }
    __syncthreads();

    u32 pooled = 0;
    if (tid < NPIX2) {
        int y14 = tid / 14;
        int x14 = tid - y14 * 14;
        int p0 = (2 * y14) * 28 + 2 * x14;
        pooled = sbyte[p0] | sbyte[p0 + 1] | sbyte[p0 + 28] | sbyte[p0 + 29];
    }

    int lane = tid & 63;
    int wv   = tid >> 6;
    u32 val = 0;
#pragma unroll
    for (int t = 0; t < 8; ++t) {
        u64 m = __ballot((pooled >> t) & 1);
        u32 piece = (lane & 1) ? (u32)(m >> 32) : (u32)m;
        if ((lane >> 1) == t) val = piece;
    }
    if (lane < 16) {
        int t = lane >> 1, half = lane & 1;
        p1bits[((size_t)(t * BATCH + b) * CH + co) * 8 + wv * 2 + half] = val;
    }
}

// ---------------------------------------------------------------------------
// K2: conv2(128->128,3x3,SAME on 14x14) + bn2, f64 accumulate.
// block = (tb, co-chunk of 16). LDS: 64ci x 16x16 f32 (zero borders), 2 halves.
// wave -> 4 co ; lane -> (row = lane>>2, 4 horizontal pixels at x0=(lane&3)*4)
// ---------------------------------------------------------------------------
__global__ __launch_bounds__(256) void k2_conv2(
    const u32* __restrict__ p1bits, const float* __restrict__ w2,
    const float* __restrict__ g2, const float* __restrict__ bb2,
    const float* __restrict__ m2, const float* __restrict__ v2,
    void* __restrict__ h2out, int is64)
{
    int blk = blockIdx.x;
    int tb = blk >> 3;
    int cc = blk & 7;
    int tid = threadIdx.x;
    int lane = tid & 63;
    int wv = __builtin_amdgcn_readfirstlane(tid >> 6);

    __shared__ float sm[64 * 256];

    float4* sm4 = (float4*)sm;
#pragma unroll
    for (int k = 0; k < 16; ++k) sm4[tid + k * 256] = make_float4(0.f, 0.f, 0.f, 0.f);
    __syncthreads();

    int row  = lane >> 2;
    int xblk = lane & 3;
    int iy = (row < 14) ? row : 13;
    int x0 = xblk * 4;
    int xb2 = (xblk < 3) ? (x0 + 4) : 8;

    int stp[4]; int stv[4];
#pragma unroll
    for (int c = 0; c < 4; ++c) {
        int p = lane + c * 64;
        int py = (p * 2341) >> 15;
        int px = p - py * 14;
        stp[c] = (py + 1) * 16 + (px + 1);
        stv[c] = (p < NPIX2);
    }

    double acc[4][4];
#pragma unroll
    for (int j = 0; j < 4; ++j)
#pragma unroll
        for (int px = 0; px < 4; ++px) acc[j][px] = 0.0;

    int t = tb >> 7, b = tb & 127;
    int co_base = cc * 16 + wv * 4;

    for (int half = 0; half < 2; ++half) {
        if (half) __syncthreads();
        for (int gg = 0; gg < 16; ++gg) {
            int ci_l = gg * 4 + wv;
            int ci = half * 64 + ci_l;
            const u32* bp = p1bits + ((size_t)(t * BATCH + b) * CH + ci) * 8;
#pragma unroll
            for (int c = 0; c < 4; ++c) {
                int p = lane + c * 64;
                if (stv[c]) {
                    u32 word = bp[p >> 5];
                    sm[ci_l * 256 + stp[c]] = ((word >> (p & 31)) & 1) ? 1.0f : 0.0f;
                }
            }
        }
        __syncthreads();

#pragma unroll 2
        for (int ci_l = 0; ci_l < 64; ++ci_l) {
            int ci = half * 64 + ci_l;
            const float* brow = sm + ci_l * 256 + iy * 16;

            double c64[3][6];
#pragma unroll
            for (int d = 0; d < 3; ++d) {
                float4 A = *(const float4*)(brow + d * 16 + x0);
                float2 E = *(const float2*)(brow + d * 16 + xb2);
                c64[d][0] = (double)A.x; c64[d][1] = (double)A.y;
                c64[d][2] = (double)A.z; c64[d][3] = (double)A.w;
                c64[d][4] = (double)E.x; c64[d][5] = (double)E.y;
            }
#pragma unroll
            for (int j = 0; j < 4; ++j) {
                int co = co_base + j;
                const float* wp = w2 + ((size_t)co * CH + ci) * 9;
                double w9[9];
#pragma unroll
                for (int k = 0; k < 9; ++k) w9[k] = (double)wp[k];
#pragma unroll
                for (int d = 0; d < 3; ++d)
#pragma unroll
                    for (int dx = 0; dx < 3; ++dx)
#pragma unroll
                        for (int px = 0; px < 4; ++px)
                            acc[j][px] += w9[d * 3 + dx] * c64[d][px + dx];
            }
        }
    }

    // epilogue: bn2 + store
    if (row < 14) {
#pragma unroll
        for (int j = 0; j < 4; ++j) {
            int co = co_base + j;
            double inv  = (double)g2[co] / sqrt((double)v2[co] + 1e-5);
            double beta = (double)bb2[co] - (double)m2[co] * inv;
#pragma unroll
            for (int px = 0; px < 4; ++px) {
                int xx = x0 + px;
                if (xx < 14) {
                    double hv = acc[j][px] * inv + beta;
                    size_t idx = ((size_t)tb * CH + co) * NPIX2 + row * 14 + xx;
                    if (is64) ((double*)h2out)[idx] = hv;
                    else      ((float*)h2out)[idx] = (float)hv;
                }
            }
        }
    }
}

// ---------------------------------------------------------------------------
// K3: IF over T on h2 + 2x2 maxpool -> z[tb][6272] u8 (0/1)
// thread = (b, ci, 7x7 window)
// ---------------------------------------------------------------------------
__global__ __launch_bounds__(256) void k3_if2_pool(
    const void* __restrict__ h2, u8* __restrict__ z, int is64)
{
    int g = blockIdx.x * 256 + threadIdx.x;
    if (g >= BATCH * CH * 49) return;
    int b = g / (CH * 49);
    int r = g - b * (CH * 49);
    int ci = r / 49;
    int w49 = r - ci * 49;
    int wy = w49 / 7, wx = w49 - wy * 7;
    int pix = (2 * wy) * 14 + 2 * wx;

    double v00 = 0, v01 = 0, v10 = 0, v11 = 0;
#pragma unroll
    for (int t = 0; t < 8; ++t) {
        size_t base = ((size_t)(t * BATCH + b) * CH + ci) * NPIX2 + pix;
        double a00, a01, a10, a11;
        if (is64) {
            const double* hp = (const double*)h2;
            double2 r0 = *(const double2*)(hp + base);
            double2 r1 = *(const double2*)(hp + base + 14);
            a00 = r0.x; a01 = r0.y; a10 = r1.x; a11 = r1.y;
        } else {
            const float* hp = (const float*)h2;
            float2 r0 = *(const float2*)(hp + base);
            float2 r1 = *(const float2*)(hp + base + 14);
            a00 = r0.x; a01 = r0.y; a10 = r1.x; a11 = r1.y;
        }
        double h0 = v00 + a00, h1 = v01 + a01, h2v = v10 + a10, h3v = v11 + a11;
        int s0 = (h0 >= 1.0), s1 = (h1 >= 1.0), s2 = (h2v >= 1.0), s3 = (h3v >= 1.0);
        v00 = s0 ? 0.0 : h0; v01 = s1 ? 0.0 : h1;
        v10 = s2 ? 0.0 : h2v; v11 = s3 ? 0.0 : h3v;
        z[(size_t)(t * BATCH + b) * FC1_IN + ci * 49 + w49] = (u8)(s0 | s1 | s2 | s3);
    }
}

// ---------------------------------------------------------------------------
// K4: fc1  h3[tb][2048] = sum_i z[tb][i] * fw[o][i], f64 accumulate.
// block: 64 o x 64 tb tile; LDS staged w (f32) and z (u8 -> f32).
// ---------------------------------------------------------------------------
__global__ __launch_bounds__(256) void k4_fc1(
    const u8* __restrict__ z, const float* __restrict__ fw,
    double* __restrict__ h3)
{
    int bx = blockIdx.x;
    int ot = bx >> 4;
    int tt = bx & 15;
    int tid = threadIdx.x;

    __shared__ float wl[64 * 68];
    __shared__ float zl[64 * 68];

    int o0 = ot * 64, tb0 = tt * 64;
    int og = tid & 15, tg = tid >> 4;
    int rr = tid >> 2, c4 = tid & 3;

    double acc[4][4];
#pragma unroll
    for (int a = 0; a < 4; ++a)
#pragma unroll
        for (int bb = 0; bb < 4; ++bb) acc[a][bb] = 0.0;

    for (int ic = 0; ic < 98; ++ic) {
        int i0 = ic * 64;
        __syncthreads();
        // stage weights: 64 rows x 64 f32
#pragma unroll
        for (int k = 0; k < 4; ++k) {
            int fc = c4 + k * 4;
            float4 wv4 = *(const float4*)(fw + (size_t)(o0 + rr) * FC1_IN + i0 + fc * 4);
            *(float4*)(wl + rr * 68 + fc * 4) = wv4;
        }
        // stage z: 64 rows x 64 bytes
        {
            const u32* zp = (const u32*)(z + (size_t)(tb0 + rr) * FC1_IN + i0 + c4 * 16);
#pragma unroll
            for (int q = 0; q < 4; ++q) {
                u32 wq = zp[q];
                float4 f;
                f.x = (float)(wq & 255u);
                f.y = (float)((wq >> 8) & 255u);
                f.z = (float)((wq >> 16) & 255u);
                f.w = (float)((wq >> 24) & 255u);
                *(float4*)(zl + rr * 68 + c4 * 16 + q * 4) = f;
            }
        }
        __syncthreads();

#pragma unroll 2
        for (int i4 = 0; i4 < 16; ++i4) {
            double wd[4][4], zd[4][4];
#pragma unroll
            for (int k = 0; k < 4; ++k) {
                float4 wv4 = *(const float4*)(wl + (og * 4 + k) * 68 + i4 * 4);
                wd[k][0] = (double)wv4.x; wd[k][1] = (double)wv4.y;
                wd[k][2] = (double)wv4.z; wd[k][3] = (double)wv4.w;
                float4 zv4 = *(const float4*)(zl + (tg * 4 + k) * 68 + i4 * 4);
                zd[k][0] = (double)zv4.x; zd[k][1] = (double)zv4.y;
                zd[k][2] = (double)zv4.z; zd[k][3] = (double)zv4.w;
            }
#pragma unroll
            for (int a = 0; a < 4; ++a)
#pragma unroll
                for (int bb = 0; bb < 4; ++bb)
#pragma unroll
                    for (int c = 0; c < 4; ++c)
                        acc[a][bb] += wd[a][c] * zd[bb][c];
        }
    }

#pragma unroll
    for (int a = 0; a < 4; ++a)
#pragma unroll
        for (int bb = 0; bb < 4; ++bb)
            h3[(size_t)(tb0 + tg * 4 + bb) * FC1_OUT + o0 + og * 4 + a] = acc[a][bb];
}

// ---------------------------------------------------------------------------
// K5: IF over T on h3 -> s3[tb][2048] u8
// ---------------------------------------------------------------------------
__global__ __launch_bounds__(256) void k5_if3(
    const double* __restrict__ h3, u8* __restrict__ s3)
{
    int g = blockIdx.x * 256 + threadIdx.x;   // 128*2048
    int b = g >> 11;
    int o = g & 2047;
    double v = 0.0;
#pragma unroll
    for (int t = 0; t < 8; ++t) {
        double h = v + h3[(size_t)(t * BATCH + b) * FC1_OUT + o];
        int s = (h >= 1.0);
        v = s ? 0.0 : h;
        s3[(size_t)(t * BATCH + b) * FC1_OUT + o] = (u8)s;
    }
}

// ---------------------------------------------------------------------------
// K6: fc2  h4[tb][16(10 used)] = sum_i s3[tb][i]*fw2[o][i], f64, wave-reduced
// ---------------------------------------------------------------------------
__global__ __launch_bounds__(64) void k6_fc2(
    const u8* __restrict__ s3, const float* __restrict__ fw2,
    double* __restrict__ h4)
{
    int tb = blockIdx.x;
    int lane = threadIdx.x;
    double acc[10];
#pragma unroll
    for (int o = 0; o < 10; ++o) acc[o] = 0.0;

    for (int k = 0; k < 32; ++k) {
        int i = k * 64 + lane;
        double zd = (double)s3[(size_t)tb * FC1_OUT + i];
#pragma unroll
        for (int o = 0; o < 10; ++o)
            acc[o] += zd * (double)fw2[o * FC1_OUT + i];
    }
#pragma unroll
    for (int o = 0; o < 10; ++o) {
#pragma unroll
        for (int off = 32; off >= 1; off >>= 1)
            acc[o] += __shfl_down(acc[o], off);
    }
    if (lane == 0) {
#pragma unroll
        for (int o = 0; o < 10; ++o) h4[(size_t)tb * 16 + o] = acc[o];
    }
}

// ---------------------------------------------------------------------------
// K7: IF over T on h4 + mean -> out[b][10] f32
// ---------------------------------------------------------------------------
__global__ __launch_bounds__(256) void k7_if4_mean(
    const double* __restrict__ h4, float* __restrict__ out)
{
    int g = blockIdx.x * 256 + threadIdx.x;
    if (g >= BATCH * FC2_OUT) return;
    int b = g / 10;
    int o = g - b * 10;
    double v = 0.0; int cnt = 0;
#pragma unroll
    for (int t = 0; t < 8; ++t) {
        double h = v + h4[(size_t)(t * BATCH + b) * 16 + o];
        int s = (h >= 1.0);
        cnt += s;
        v = s ? 0.0 : h;
    }
    out[b * 10 + o] = (float)cnt * 0.125f;
}

// ---------------------------------------------------------------------------
extern "C" void kernel_launch(void* const* d_in, const int* in_sizes, int n_in,
                              void* d_out, int out_size, void* d_ws, size_t ws_size,
                              hipStream_t stream)
{
    const float* x   = (const float*)d_in[0];
    const float* w1  = (const float*)d_in[1];
    const float* g1  = (const float*)d_in[2];
    const float* b1  = (const float*)d_in[3];
    const float* m1  = (const float*)d_in[4];
    const float* v1  = (const float*)d_in[5];
    const float* w2  = (const float*)d_in[6];
    const float* g2  = (const float*)d_in[7];
    const float* b2  = (const float*)d_in[8];
    const float* m2  = (const float*)d_in[9];
    const float* v2  = (const float*)d_in[10];
    const float* fw1 = (const float*)d_in[11];
    const float* fw2 = (const float*)d_in[12];
    float* out = (float*)d_out;

    char* ws = (char*)d_ws;
    size_t off = 0;
    auto alloc = [&](size_t sz) { size_t o = off; off = (off + sz + 255) & ~(size_t)255; return o; };

    size_t o_p1 = alloc((size_t)TSTEPS * BATCH * CH * 8 * 4);   // 4 MB
    size_t o_z  = alloc((size_t)TB * FC1_IN);                   // 6.4 MB
    size_t o_h3 = alloc((size_t)TB * FC1_OUT * 8);              // 16.8 MB
    size_t o_s3 = alloc((size_t)TB * FC1_OUT);                  // 2.1 MB
    size_t o_h4 = alloc((size_t)TB * 16 * 8);                   // 128 KB
    size_t o_h2 = off;
    size_t h2_f64_bytes = (size_t)TB * CH * NPIX2 * 8;          // 205.5 MB
    int is64 = (off + h2_f64_bytes <= ws_size) ? 1 : 0;

    u32*    p1bits = (u32*)(ws + o_p1);
    u8*     z      = (u8*)(ws + o_z);
    double* h3     = (double*)(ws + o_h3);
    u8*     s3     = (u8*)(ws + o_s3);
    double* h4     = (double*)(ws + o_h4);
    void*   h2     = (void*)(ws + o_h2);

    k1_conv1_if_pool<<<dim3(BATCH * CH), dim3(256), 0, stream>>>(
        x, w1, g1, b1, m1, v1, p1bits);

    k2_conv2<<<dim3(TB * 8), dim3(256), 0, stream>>>(
        p1bits, w2, g2, b2, m2, v2, h2, is64);

    k3_if2_pool<<<dim3((BATCH * CH * 49 + 255) / 256), dim3(256), 0, stream>>>(
        h2, z, is64);

    k4_fc1<<<dim3(32 * 16), dim3(256), 0, stream>>>(z, fw1, h3);

    k5_if3<<<dim3(BATCH * FC1_OUT / 256), dim3(256), 0, stream>>>(h3, s3);

    k6_fc2<<<dim3(TB), dim3(64), 0, stream>>>(s3, fw2, h4);

    k7_if4_mean<<<dim3((BATCH * FC2_OUT + 255) / 256), dim3(256), 0, stream>>>(h4, out);
}

// Round 2
// 1593.146 us; speedup vs baseline: 1.5854x; 1.5854x over previous
//
#include <hip/hip_runtime.h>
#include <stdint.h>

typedef unsigned int u32;
typedef unsigned long long u64;
typedef unsigned char u8;
typedef signed char s8;
typedef int v4i __attribute__((ext_vector_type(4)));
typedef int v16i __attribute__((ext_vector_type(16)));

#define TSTEPS 8
#define BATCH 128
#define CH 128
#define NPIX1 784   // 28*28
#define NPIX2 196   // 14*14
#define TB 1024     // TSTEPS*BATCH
#define FC1_OUT 2048
#define FC1_IN 6272 // 128*49
#define FC2_OUT 10

#define W2_DIGITS 5
#define W2_SCALE 34359738368.0          // 2^35
#define W2_INVSCALE 2.9103830456733704e-11  // 2^-35

// ---------------------------------------------------------------------------
// K1: conv1(1->128,3x3,SAME) + bn1 + IF over T=8 (constant input) + 2x2 maxpool
// output: p1bits[t][b][ci][8 u32]  (bit p = pooled spike at 14x14 pixel p)
// ---------------------------------------------------------------------------
__global__ __launch_bounds__(256) void k1_conv1_if_pool(
    const float* __restrict__ x, const float* __restrict__ w1,
    const float* __restrict__ g1, const float* __restrict__ b1,
    const float* __restrict__ m1, const float* __restrict__ v1,
    u32* __restrict__ p1bits)
{
    int blk = blockIdx.x;
    int b  = blk >> 7;
    int co = blk & 127;
    int tid = threadIdx.x;

    __shared__ u32 sbyte[NPIX1];

    double wk[9];
#pragma unroll
    for (int k = 0; k < 9; ++k) wk[k] = (double)w1[co * 9 + k];
    double inv  = (double)g1[co] / sqrt((double)v1[co] + 1e-5);
    double beta = (double)b1[co] - (double)m1[co] * inv;

    const float* xb = x + (size_t)b * NPIX1;

    for (int p = tid; p < NPIX1; p += 256) {
        int y  = p / 28;
        int xx = p - y * 28;
        double acc = 0.0;
#pragma unroll
        for (int dy = 0; dy < 3; ++dy) {
            int iy = y + dy - 1;
#pragma unroll
            for (int dx = 0; dx < 3; ++dx) {
                int ix = xx + dx - 1;
                if (iy >= 0 && iy < 28 && ix >= 0 && ix < 28)
                    acc += (double)xb[iy * 28 + ix] * wk[dy * 3 + dx];
            }
        }
        double yv = acc * inv + beta;
        double v = 0.0; u32 byte = 0;
#pragma unroll
        for (int t = 0; t < 8; ++t) {
            double h = v + yv;
            int s = (h >= 1.0);
            byte |= (u32)s << t;
            v = s ? 0.0 : h;
        }
        sbyte[p] = byte;
    }
    __syncthreads();

    u32 pooled = 0;
    if (tid < NPIX2) {
        int y14 = tid / 14;
        int x14 = tid - y14 * 14;
        int p0 = (2 * y14) * 28 + 2 * x14;
        pooled = sbyte[p0] | sbyte[p0 + 1] | sbyte[p0 + 28] | sbyte[p0 + 29];
    }

    int lane = tid & 63;
    int wv   = tid >> 6;
    u32 val = 0;
#pragma unroll
    for (int t = 0; t < 8; ++t) {
        u64 m = __ballot((pooled >> t) & 1);
        u32 piece = (lane & 1) ? (u32)(m >> 32) : (u32)m;
        if ((lane >> 1) == t) val = piece;
    }
    if (lane < 16) {
        int t = lane >> 1, half = lane & 1;
        p1bits[((size_t)(t * BATCH + b) * CH + co) * 8 + wv * 2 + half] = val;
    }
}

// ---------------------------------------------------------------------------
// K2w: quantize conv2 weights to 5 signed base-128 digits at scale 2^35.
// Wd[d][tap][co][ci] i8.  Exact: sum_d dg_d*128^d == llrint(w*2^35).
// ---------------------------------------------------------------------------
__global__ __launch_bounds__(256) void k2w_quant(
    const float* __restrict__ w2, s8* __restrict__ Wd)
{
    int g = blockIdx.x * 256 + threadIdx.x;   // co*128+ci
    if (g >= CH * CH) return;
    int co = g >> 7, ci = g & 127;
#pragma unroll
    for (int k = 0; k < 9; ++k) {
        double wd = (double)w2[(size_t)g * 9 + k] * W2_SCALE;
        long r = (long)llrint(wd);
#pragma unroll
        for (int d = 0; d < W2_DIGITS; ++d) {
            int dg = (int)(r & 127);
            if (dg >= 64) dg -= 128;
            r = (r - (long)dg) >> 7;
            Wd[(((size_t)d * 9 + k) * CH + co) * CH + ci] = (s8)dg;
        }
    }
}

// ---------------------------------------------------------------------------
// K2: conv2 via exact fixed-point i8 MFMA implicit GEMM.
// block = one (t,b); 512 threads = 8 waves; wave w -> M-tile w (32 pixels),
// N-tiles 0..3 (all 128 co). Spikes staged in LDS [16x16 halo rows][128 ci]
// with XOR-((row&7)<<4) swizzle. Digit loop outer, i64 carry recombination.
// Output h2T[tb][pix][ci] f64 (or f32 fallback), bn2 fused.
// ---------------------------------------------------------------------------
__global__ __launch_bounds__(512, 2) void k2_conv2_i8(
    const u32* __restrict__ p1bits, const s8* __restrict__ Wd,
    const float* __restrict__ g2, const float* __restrict__ bb2,
    const float* __restrict__ m2, const float* __restrict__ v2,
    void* __restrict__ h2T, int is64)
{
    int tb = blockIdx.x;
    int tid = threadIdx.x;
    int lane = tid & 63;
    int wv = tid >> 6;            // M tile 0..7 (pixels wv*32..wv*32+31)
    int lane32 = lane & 31;
    int khalf = (lane >> 5) << 4; // K half offset in bytes

    __shared__ u8 sp[32768];      // [row 0..255][ci 0..127], swizzled

    uint4* sp16 = (uint4*)sp;
#pragma unroll
    for (int q = 0; q < 4; ++q) sp16[tid + q * 512] = make_uint4(0u, 0u, 0u, 0u);
    __syncthreads();

    // stage spikes: bit -> i8, halo border stays 0
    for (int c = tid; c < NPIX2 * 8; c += 512) {
        int p = c >> 3, cg = c & 7;
        int ci0 = cg * 16;
        int py = (p * 2341) >> 15;
        int px = p - py * 14;
        int row = (py + 1) * 16 + (px + 1);
        int wi = p >> 5, bit = p & 31;
        const u32* bp = p1bits + ((size_t)tb * CH + ci0) * 8 + wi;
        u32 wd0 = 0, wd1 = 0, wd2 = 0, wd3 = 0;
#pragma unroll
        for (int j = 0; j < 4; ++j) {
            wd0 |= ((bp[(j     ) * 8] >> bit) & 1u) << (j * 8);
            wd1 |= ((bp[(j +  4) * 8] >> bit) & 1u) << (j * 8);
            wd2 |= ((bp[(j +  8) * 8] >> bit) & 1u) << (j * 8);
            wd3 |= ((bp[(j + 12) * 8] >> bit) & 1u) << (j * 8);
        }
        int addr = (row * 128 + ci0) ^ ((row & 7) << 4);
        *(uint4*)(sp + addr) = make_uint4(wd0, wd1, wd2, wd3);
    }
    __syncthreads();

    int p  = wv * 32 + lane32;
    int pe = (p < NPIX2) ? p : (NPIX2 - 1);
    int py = (pe * 2341) >> 15;
    int px = pe - py * 14;
    int rb = py * 16 + px;        // + dy*16+dx gives halo row index

    long carry0[16], carry1[16], carry2[16], carry3[16];
#pragma unroll
    for (int r = 0; r < 16; ++r) { carry0[r] = 0; carry1[r] = 0; carry2[r] = 0; carry3[r] = 0; }

#pragma unroll 1
    for (int d = 0; d < W2_DIGITS; ++d) {
        v16i a0, a1, a2, a3;
#pragma unroll
        for (int r = 0; r < 16; ++r) { a0[r] = 0; a1[r] = 0; a2[r] = 0; a3[r] = 0; }

#pragma unroll 1
        for (int tap = 0; tap < 9; ++tap) {
            int dy = tap / 3;
            int dx = tap - dy * 3;
            int rowidx = rb + dy * 16 + dx;
            int swz = (rowidx & 7) << 4;
            const s8* wl = Wd + ((size_t)(d * 9 + tap) << 14) + lane32 * 128 + khalf;
#pragma unroll
            for (int ks = 0; ks < 4; ++ks) {
                v4i A  = *(const v4i*)(sp + ((rowidx * 128 + ks * 32 + khalf) ^ swz));
                v4i B0 = *(const v4i*)(wl + ks * 32);
                v4i B1 = *(const v4i*)(wl + ks * 32 + 32 * 128);
                v4i B2 = *(const v4i*)(wl + ks * 32 + 64 * 128);
                v4i B3 = *(const v4i*)(wl + ks * 32 + 96 * 128);
                a0 = __builtin_amdgcn_mfma_i32_32x32x32_i8(A, B0, a0, 0, 0, 0);
                a1 = __builtin_amdgcn_mfma_i32_32x32x32_i8(A, B1, a1, 0, 0, 0);
                a2 = __builtin_amdgcn_mfma_i32_32x32x32_i8(A, B2, a2, 0, 0, 0);
                a3 = __builtin_amdgcn_mfma_i32_32x32x32_i8(A, B3, a3, 0, 0, 0);
            }
        }
        int sh = 7 * d;
#pragma unroll
        for (int r = 0; r < 16; ++r) {
            carry0[r] += ((long)a0[r]) << sh;
            carry1[r] += ((long)a1[r]) << sh;
            carry2[r] += ((long)a2[r]) << sh;
            carry3[r] += ((long)a3[r]) << sh;
        }
    }

    int rhi = (lane >> 5) * 4;
#define EPILOGUE(NT, CARR)                                                    \
    {                                                                         \
        int co = NT * 32 + lane32;                                            \
        double inv  = (double)g2[co] / sqrt((double)v2[co] + 1e-5);           \
        double beta = (double)bb2[co] - (double)m2[co] * inv;                 \
        _Pragma("unroll")                                                     \
        for (int r = 0; r < 16; ++r) {                                        \
            int pix = wv * 32 + (r & 3) + 8 * (r >> 2) + rhi;                 \
            if (pix < NPIX2) {                                                \
                double h = (double)CARR[r] * W2_INVSCALE * inv + beta;        \
                size_t idx = ((size_t)tb * NPIX2 + pix) * CH + co;            \
                if (is64) ((double*)h2T)[idx] = h;                            \
                else      ((float*)h2T)[idx] = (float)h;                      \
            }                                                                 \
        }                                                                     \
    }
    EPILOGUE(0, carry0)
    EPILOGUE(1, carry1)
    EPILOGUE(2, carry2)
    EPILOGUE(3, carry3)
#undef EPILOGUE
}

// ---------------------------------------------------------------------------
// K3: IF over T on h2T + 2x2 maxpool -> z[tb][6272] u8 (0/1)
// thread = (b, 7x7 window, ci) with ci fastest -> coalesced h2T reads
// ---------------------------------------------------------------------------
__global__ __launch_bounds__(256) void k3_if2_pool(
    const void* __restrict__ h2T, u8* __restrict__ z, int is64)
{
    int g = blockIdx.x * 256 + threadIdx.x;   // 128*49*128 = 802816
    int ci = g & 127;
    int rest = g >> 7;
    int b = rest / 49;
    int w49 = rest - b * 49;
    int wy = w49 / 7, wx = w49 - wy * 7;
    int pix = (2 * wy) * 14 + 2 * wx;

    double v00 = 0, v01 = 0, v10 = 0, v11 = 0;
#pragma unroll
    for (int t = 0; t < 8; ++t) {
        size_t base = ((size_t)(t * BATCH + b) * NPIX2 + pix) * CH + ci;
        double a00, a01, a10, a11;
        if (is64) {
            const double* hp = (const double*)h2T;
            a00 = hp[base];            a01 = hp[base + CH];
            a10 = hp[base + 14 * CH];  a11 = hp[base + 15 * CH];
        } else {
            const float* hp = (const float*)h2T;
            a00 = (double)hp[base];           a01 = (double)hp[base + CH];
            a10 = (double)hp[base + 14 * CH]; a11 = (double)hp[base + 15 * CH];
        }
        double h0 = v00 + a00, h1 = v01 + a01, h2v = v10 + a10, h3v = v11 + a11;
        int s0 = (h0 >= 1.0), s1 = (h1 >= 1.0), s2 = (h2v >= 1.0), s3 = (h3v >= 1.0);
        v00 = s0 ? 0.0 : h0; v01 = s1 ? 0.0 : h1;
        v10 = s2 ? 0.0 : h2v; v11 = s3 ? 0.0 : h3v;
        z[(size_t)(t * BATCH + b) * FC1_IN + ci * 49 + w49] = (u8)(s0 | s1 | s2 | s3);
    }
}

// ---------------------------------------------------------------------------
// K4: fc1  h3[tb][2048] = sum_i z[tb][i] * fw[o][i], f64 accumulate.
// ---------------------------------------------------------------------------
__global__ __launch_bounds__(256) void k4_fc1(
    const u8* __restrict__ z, const float* __restrict__ fw,
    double* __restrict__ h3)
{
    int bx = blockIdx.x;
    int ot = bx >> 4;
    int tt = bx & 15;
    int tid = threadIdx.x;

    __shared__ float wl[64 * 68];
    __shared__ float zl[64 * 68];

    int o0 = ot * 64, tb0 = tt * 64;
    int og = tid & 15, tg = tid >> 4;
    int rr = tid >> 2, c4 = tid & 3;

    double acc[4][4];
#pragma unroll
    for (int a = 0; a < 4; ++a)
#pragma unroll
        for (int bb = 0; bb < 4; ++bb) acc[a][bb] = 0.0;

    for (int ic = 0; ic < 98; ++ic) {
        int i0 = ic * 64;
        __syncthreads();
#pragma unroll
        for (int k = 0; k < 4; ++k) {
            int fc = c4 + k * 4;
            float4 wv4 = *(const float4*)(fw + (size_t)(o0 + rr) * FC1_IN + i0 + fc * 4);
            *(float4*)(wl + rr * 68 + fc * 4) = wv4;
        }
        {
            const u32* zp = (const u32*)(z + (size_t)(tb0 + rr) * FC1_IN + i0 + c4 * 16);
#pragma unroll
            for (int q = 0; q < 4; ++q) {
                u32 wq = zp[q];
                float4 f;
                f.x = (float)(wq & 255u);
                f.y = (float)((wq >> 8) & 255u);
                f.z = (float)((wq >> 16) & 255u);
                f.w = (float)((wq >> 24) & 255u);
                *(float4*)(zl + rr * 68 + c4 * 16 + q * 4) = f;
            }
        }
        __syncthreads();

#pragma unroll 2
        for (int i4 = 0; i4 < 16; ++i4) {
            double wd[4][4], zd[4][4];
#pragma unroll
            for (int k = 0; k < 4; ++k) {
                float4 wv4 = *(const float4*)(wl + (og * 4 + k) * 68 + i4 * 4);
                wd[k][0] = (double)wv4.x; wd[k][1] = (double)wv4.y;
                wd[k][2] = (double)wv4.z; wd[k][3] = (double)wv4.w;
                float4 zv4 = *(const float4*)(zl + (tg * 4 + k) * 68 + i4 * 4);
                zd[k][0] = (double)zv4.x; zd[k][1] = (double)zv4.y;
                zd[k][2] = (double)zv4.z; zd[k][3] = (double)zv4.w;
            }
#pragma unroll
            for (int a = 0; a < 4; ++a)
#pragma unroll
                for (int bb = 0; bb < 4; ++bb)
#pragma unroll
                    for (int c = 0; c < 4; ++c)
                        acc[a][bb] += wd[a][c] * zd[bb][c];
        }
    }

#pragma unroll
    for (int a = 0; a < 4; ++a)
#pragma unroll
        for (int bb = 0; bb < 4; ++bb)
            h3[(size_t)(tb0 + tg * 4 + bb) * FC1_OUT + o0 + og * 4 + a] = acc[a][bb];
}

// ---------------------------------------------------------------------------
// K5: IF over T on h3 -> s3[tb][2048] u8
// ---------------------------------------------------------------------------
__global__ __launch_bounds__(256) void k5_if3(
    const double* __restrict__ h3, u8* __restrict__ s3)
{
    int g = blockIdx.x * 256 + threadIdx.x;
    int b = g >> 11;
    int o = g & 2047;
    double v = 0.0;
#pragma unroll
    for (int t = 0; t < 8; ++t) {
        double h = v + h3[(size_t)(t * BATCH + b) * FC1_OUT + o];
        int s = (h >= 1.0);
        v = s ? 0.0 : h;
        s3[(size_t)(t * BATCH + b) * FC1_OUT + o] = (u8)s;
    }
}

// ---------------------------------------------------------------------------
// K6: fc2  h4[tb][16(10 used)] = sum_i s3[tb][i]*fw2[o][i], f64, wave-reduced
// ---------------------------------------------------------------------------
__global__ __launch_bounds__(64) void k6_fc2(
    const u8* __restrict__ s3, const float* __restrict__ fw2,
    double* __restrict__ h4)
{
    int tb = blockIdx.x;
    int lane = threadIdx.x;
    double acc[10];
#pragma unroll
    for (int o = 0; o < 10; ++o) acc[o] = 0.0;

    for (int k = 0; k < 32; ++k) {
        int i = k * 64 + lane;
        double zd = (double)s3[(size_t)tb * FC1_OUT + i];
#pragma unroll
        for (int o = 0; o < 10; ++o)
            acc[o] += zd * (double)fw2[o * FC1_OUT + i];
    }
#pragma unroll
    for (int o = 0; o < 10; ++o) {
#pragma unroll
        for (int off = 32; off >= 1; off >>= 1)
            acc[o] += __shfl_down(acc[o], off);
    }
    if (lane == 0) {
#pragma unroll
        for (int o = 0; o < 10; ++o) h4[(size_t)tb * 16 + o] = acc[o];
    }
}

// ---------------------------------------------------------------------------
// K7: IF over T on h4 + mean -> out[b][10] f32
// ---------------------------------------------------------------------------
__global__ __launch_bounds__(256) void k7_if4_mean(
    const double* __restrict__ h4, float* __restrict__ out)
{
    int g = blockIdx.x * 256 + threadIdx.x;
    if (g >= BATCH * FC2_OUT) return;
    int b = g / 10;
    int o = g - b * 10;
    double v = 0.0; int cnt = 0;
#pragma unroll
    for (int t = 0; t < 8; ++t) {
        double h = v + h4[(size_t)(t * BATCH + b) * 16 + o];
        int s = (h >= 1.0);
        cnt += s;
        v = s ? 0.0 : h;
    }
    out[b * 10 + o] = (float)cnt * 0.125f;
}

// ---------------------------------------------------------------------------
extern "C" void kernel_launch(void* const* d_in, const int* in_sizes, int n_in,
                              void* d_out, int out_size, void* d_ws, size_t ws_size,
                              hipStream_t stream)
{
    const float* x   = (const float*)d_in[0];
    const float* w1  = (const float*)d_in[1];
    const float* g1  = (const float*)d_in[2];
    const float* b1  = (const float*)d_in[3];
    const float* m1  = (const float*)d_in[4];
    const float* v1  = (const float*)d_in[5];
    const float* w2  = (const float*)d_in[6];
    const float* g2  = (const float*)d_in[7];
    const float* b2  = (const float*)d_in[8];
    const float* m2  = (const float*)d_in[9];
    const float* v2  = (const float*)d_in[10];
    const float* fw1 = (const float*)d_in[11];
    const float* fw2 = (const float*)d_in[12];
    float* out = (float*)d_out;

    char* ws = (char*)d_ws;
    size_t off = 0;
    auto alloc = [&](size_t sz) { size_t o = off; off = (off + sz + 255) & ~(size_t)255; return o; };

    size_t o_p1 = alloc((size_t)TSTEPS * BATCH * CH * 8 * 4);   // 4 MB
    size_t o_z  = alloc((size_t)TB * FC1_IN);                   // 6.4 MB
    size_t o_h3 = alloc((size_t)TB * FC1_OUT * 8);              // 16.8 MB
    size_t o_s3 = alloc((size_t)TB * FC1_OUT);                  // 2.1 MB
    size_t o_h4 = alloc((size_t)TB * 16 * 8);                   // 128 KB
    size_t o_wd = alloc((size_t)W2_DIGITS * 9 * CH * CH);       // 737 KB
    size_t o_h2 = off;
    size_t h2_f64_bytes = (size_t)TB * CH * NPIX2 * 8;          // 205.5 MB
    int is64 = (off + h2_f64_bytes <= ws_size) ? 1 : 0;

    u32*    p1bits = (u32*)(ws + o_p1);
    u8*     z      = (u8*)(ws + o_z);
    double* h3     = (double*)(ws + o_h3);
    u8*     s3     = (u8*)(ws + o_s3);
    double* h4     = (double*)(ws + o_h4);
    s8*     Wd     = (s8*)(ws + o_wd);
    void*   h2T    = (void*)(ws + o_h2);

    k2w_quant<<<dim3((CH * CH + 255) / 256), dim3(256), 0, stream>>>(w2, Wd);

    k1_conv1_if_pool<<<dim3(BATCH * CH), dim3(256), 0, stream>>>(
        x, w1, g1, b1, m1, v1, p1bits);

    k2_conv2_i8<<<dim3(TB), dim3(512), 0, stream>>>(
        p1bits, Wd, g2, b2, m2, v2, h2T, is64);

    k3_if2_pool<<<dim3(BATCH * 49 * CH / 256), dim3(256), 0, stream>>>(
        h2T, z, is64);

    k4_fc1<<<dim3(32 * 16), dim3(256), 0, stream>>>(z, fw1, h3);

    k5_if3<<<dim3(BATCH * FC1_OUT / 256), dim3(256), 0, stream>>>(h3, s3);

    k6_fc2<<<dim3(TB), dim3(64), 0, stream>>>(s3, fw2, h4);

    k7_if4_mean<<<dim3((BATCH * FC2_OUT + 255) / 256), dim3(256), 0, stream>>>(h4, out);
}

// Round 3
// 1454.727 us; speedup vs baseline: 1.7363x; 1.0952x over previous
//
#include <hip/hip_runtime.h>
#include <stdint.h>

typedef unsigned int u32;
typedef unsigned long long u64;
typedef unsigned char u8;
typedef signed char s8;
typedef int v4i __attribute__((ext_vector_type(4)));
typedef int v16i __attribute__((ext_vector_type(16)));

#define TSTEPS 8
#define BATCH 128
#define CH 128
#define NPIX1 784   // 28*28
#define NPIX2 196   // 14*14
#define TB 1024     // TSTEPS*BATCH
#define FC1_OUT 2048
#define FC1_IN 6272 // 128*49
#define FC2_OUT 10

#define W2_DIGITS 5
#define W2_SCALE 34359738368.0              // 2^35
#define W2_INVSCALE 2.9103830456733704e-11  // 2^-35

#define FC1_DIGITS 6
#define FC1_KB 196                          // 6272/32
#define FC1_SCALE 1099511627776.0           // 2^40
#define FC1_INVSCALE 9.094947017729282e-13  // 2^-40

// ---------------------------------------------------------------------------
// K1: conv1(1->128,3x3,SAME) + bn1 + IF over T=8 (constant input) + 2x2 maxpool
// output: p1bits[t][b][ci][8 u32]  (bit p = pooled spike at 14x14 pixel p)
// ---------------------------------------------------------------------------
__global__ __launch_bounds__(256) void k1_conv1_if_pool(
    const float* __restrict__ x, const float* __restrict__ w1,
    const float* __restrict__ g1, const float* __restrict__ b1,
    const float* __restrict__ m1, const float* __restrict__ v1,
    u32* __restrict__ p1bits)
{
    int blk = blockIdx.x;
    int b  = blk >> 7;
    int co = blk & 127;
    int tid = threadIdx.x;

    __shared__ u32 sbyte[NPIX1];

    double wk[9];
#pragma unroll
    for (int k = 0; k < 9; ++k) wk[k] = (double)w1[co * 9 + k];
    double inv  = (double)g1[co] / sqrt((double)v1[co] + 1e-5);
    double beta = (double)b1[co] - (double)m1[co] * inv;

    const float* xb = x + (size_t)b * NPIX1;

    for (int p = tid; p < NPIX1; p += 256) {
        int y  = p / 28;
        int xx = p - y * 28;
        double acc = 0.0;
#pragma unroll
        for (int dy = 0; dy < 3; ++dy) {
            int iy = y + dy - 1;
#pragma unroll
            for (int dx = 0; dx < 3; ++dx) {
                int ix = xx + dx - 1;
                if (iy >= 0 && iy < 28 && ix >= 0 && ix < 28)
                    acc += (double)xb[iy * 28 + ix] * wk[dy * 3 + dx];
            }
        }
        double yv = acc * inv + beta;
        double v = 0.0; u32 byte = 0;
#pragma unroll
        for (int t = 0; t < 8; ++t) {
            double h = v + yv;
            int s = (h >= 1.0);
            byte |= (u32)s << t;
            v = s ? 0.0 : h;
        }
        sbyte[p] = byte;
    }
    __syncthreads();

    u32 pooled = 0;
    if (tid < NPIX2) {
        int y14 = tid / 14;
        int x14 = tid - y14 * 14;
        int p0 = (2 * y14) * 28 + 2 * x14;
        pooled = sbyte[p0] | sbyte[p0 + 1] | sbyte[p0 + 28] | sbyte[p0 + 29];
    }

    int lane = tid & 63;
    int wv   = tid >> 6;
    u32 val = 0;
#pragma unroll
    for (int t = 0; t < 8; ++t) {
        u64 m = __ballot((pooled >> t) & 1);
        u32 piece = (lane & 1) ? (u32)(m >> 32) : (u32)m;
        if ((lane >> 1) == t) val = piece;
    }
    if (lane < 16) {
        int t = lane >> 1, half = lane & 1;
        p1bits[((size_t)(t * BATCH + b) * CH + co) * 8 + wv * 2 + half] = val;
    }
}

// ---------------------------------------------------------------------------
// K2w: quantize conv2 weights to 5 signed base-128 digits at scale 2^35.
// Wd[d][tap][co][ci] i8.  Exact: sum_d dg_d*128^d == llrint(w*2^35).
// ---------------------------------------------------------------------------
__global__ __launch_bounds__(256) void k2w_quant(
    const float* __restrict__ w2, s8* __restrict__ Wd)
{
    int g = blockIdx.x * 256 + threadIdx.x;   // co*128+ci
    if (g >= CH * CH) return;
    int co = g >> 7, ci = g & 127;
#pragma unroll
    for (int k = 0; k < 9; ++k) {
        double wd = (double)w2[(size_t)g * 9 + k] * W2_SCALE;
        long r = (long)llrint(wd);
#pragma unroll
        for (int d = 0; d < W2_DIGITS; ++d) {
            int dg = (int)(r & 127);
            if (dg >= 64) dg -= 128;
            r = (r - (long)dg) >> 7;
            Wd[(((size_t)d * 9 + k) * CH + co) * CH + ci] = (s8)dg;
        }
    }
}

// ---------------------------------------------------------------------------
// K2: conv2 via exact fixed-point i8 MFMA implicit GEMM.
// ---------------------------------------------------------------------------
__global__ __launch_bounds__(512, 2) void k2_conv2_i8(
    const u32* __restrict__ p1bits, const s8* __restrict__ Wd,
    const float* __restrict__ g2, const float* __restrict__ bb2,
    const float* __restrict__ m2, const float* __restrict__ v2,
    void* __restrict__ h2T, int is64)
{
    int tb = blockIdx.x;
    int tid = threadIdx.x;
    int lane = tid & 63;
    int wv = tid >> 6;            // M tile 0..7 (pixels wv*32..wv*32+31)
    int lane32 = lane & 31;
    int khalf = (lane >> 5) << 4; // K half offset in bytes

    __shared__ u8 sp[32768];      // [row 0..255][ci 0..127], swizzled

    uint4* sp16 = (uint4*)sp;
#pragma unroll
    for (int q = 0; q < 4; ++q) sp16[tid + q * 512] = make_uint4(0u, 0u, 0u, 0u);
    __syncthreads();

    for (int c = tid; c < NPIX2 * 8; c += 512) {
        int p = c >> 3, cg = c & 7;
        int ci0 = cg * 16;
        int py = (p * 2341) >> 15;
        int px = p - py * 14;
        int row = (py + 1) * 16 + (px + 1);
        int wi = p >> 5, bit = p & 31;
        const u32* bp = p1bits + ((size_t)tb * CH + ci0) * 8 + wi;
        u32 wd0 = 0, wd1 = 0, wd2 = 0, wd3 = 0;
#pragma unroll
        for (int j = 0; j < 4; ++j) {
            wd0 |= ((bp[(j     ) * 8] >> bit) & 1u) << (j * 8);
            wd1 |= ((bp[(j +  4) * 8] >> bit) & 1u) << (j * 8);
            wd2 |= ((bp[(j +  8) * 8] >> bit) & 1u) << (j * 8);
            wd3 |= ((bp[(j + 12) * 8] >> bit) & 1u) << (j * 8);
        }
        int addr = (row * 128 + ci0) ^ ((row & 7) << 4);
        *(uint4*)(sp + addr) = make_uint4(wd0, wd1, wd2, wd3);
    }
    __syncthreads();

    int p  = wv * 32 + lane32;
    int pe = (p < NPIX2) ? p : (NPIX2 - 1);
    int py = (pe * 2341) >> 15;
    int px = pe - py * 14;
    int rb = py * 16 + px;

    long carry0[16], carry1[16], carry2[16], carry3[16];
#pragma unroll
    for (int r = 0; r < 16; ++r) { carry0[r] = 0; carry1[r] = 0; carry2[r] = 0; carry3[r] = 0; }

#pragma unroll 1
    for (int d = 0; d < W2_DIGITS; ++d) {
        v16i a0, a1, a2, a3;
#pragma unroll
        for (int r = 0; r < 16; ++r) { a0[r] = 0; a1[r] = 0; a2[r] = 0; a3[r] = 0; }

#pragma unroll 1
        for (int tap = 0; tap < 9; ++tap) {
            int dy = tap / 3;
            int dx = tap - dy * 3;
            int rowidx = rb + dy * 16 + dx;
            int swz = (rowidx & 7) << 4;
            const s8* wl = Wd + ((size_t)(d * 9 + tap) << 14) + lane32 * 128 + khalf;
#pragma unroll
            for (int ks = 0; ks < 4; ++ks) {
                v4i A  = *(const v4i*)(sp + ((rowidx * 128 + ks * 32 + khalf) ^ swz));
                v4i B0 = *(const v4i*)(wl + ks * 32);
                v4i B1 = *(const v4i*)(wl + ks * 32 + 32 * 128);
                v4i B2 = *(const v4i*)(wl + ks * 32 + 64 * 128);
                v4i B3 = *(const v4i*)(wl + ks * 32 + 96 * 128);
                a0 = __builtin_amdgcn_mfma_i32_32x32x32_i8(A, B0, a0, 0, 0, 0);
                a1 = __builtin_amdgcn_mfma_i32_32x32x32_i8(A, B1, a1, 0, 0, 0);
                a2 = __builtin_amdgcn_mfma_i32_32x32x32_i8(A, B2, a2, 0, 0, 0);
                a3 = __builtin_amdgcn_mfma_i32_32x32x32_i8(A, B3, a3, 0, 0, 0);
            }
        }
        int sh = 7 * d;
#pragma unroll
        for (int r = 0; r < 16; ++r) {
            carry0[r] += ((long)a0[r]) << sh;
            carry1[r] += ((long)a1[r]) << sh;
            carry2[r] += ((long)a2[r]) << sh;
            carry3[r] += ((long)a3[r]) << sh;
        }
    }

    int rhi = (lane >> 5) * 4;
#define EPILOGUE(NT, CARR)                                                    \
    {                                                                         \
        int co = NT * 32 + lane32;                                            \
        double inv  = (double)g2[co] / sqrt((double)v2[co] + 1e-5);           \
        double beta = (double)bb2[co] - (double)m2[co] * inv;                 \
        _Pragma("unroll")                                                     \
        for (int r = 0; r < 16; ++r) {                                        \
            int pix = wv * 32 + (r & 3) + 8 * (r >> 2) + rhi;                 \
            if (pix < NPIX2) {                                                \
                double h = (double)CARR[r] * W2_INVSCALE * inv + beta;        \
                size_t idx = ((size_t)tb * NPIX2 + pix) * CH + co;            \
                if (is64) ((double*)h2T)[idx] = h;                            \
                else      ((float*)h2T)[idx] = (float)h;                      \
            }                                                                 \
        }                                                                     \
    }
    EPILOGUE(0, carry0)
    EPILOGUE(1, carry1)
    EPILOGUE(2, carry2)
    EPILOGUE(3, carry3)
#undef EPILOGUE
}

// ---------------------------------------------------------------------------
// K3: IF over T on h2T + 2x2 maxpool -> z[tb][6272] u8 (0/1)
// ---------------------------------------------------------------------------
__global__ __launch_bounds__(256) void k3_if2_pool(
    const void* __restrict__ h2T, u8* __restrict__ z, int is64)
{
    int g = blockIdx.x * 256 + threadIdx.x;   // 128*49*128 = 802816
    int ci = g & 127;
    int rest = g >> 7;
    int b = rest / 49;
    int w49 = rest - b * 49;
    int wy = w49 / 7, wx = w49 - wy * 7;
    int pix = (2 * wy) * 14 + 2 * wx;

    double v00 = 0, v01 = 0, v10 = 0, v11 = 0;
#pragma unroll
    for (int t = 0; t < 8; ++t) {
        size_t base = ((size_t)(t * BATCH + b) * NPIX2 + pix) * CH + ci;
        double a00, a01, a10, a11;
        if (is64) {
            const double* hp = (const double*)h2T;
            a00 = hp[base];            a01 = hp[base + CH];
            a10 = hp[base + 14 * CH];  a11 = hp[base + 15 * CH];
        } else {
            const float* hp = (const float*)h2T;
            a00 = (double)hp[base];           a01 = (double)hp[base + CH];
            a10 = (double)hp[base + 14 * CH]; a11 = (double)hp[base + 15 * CH];
        }
        double h0 = v00 + a00, h1 = v01 + a01, h2v = v10 + a10, h3v = v11 + a11;
        int s0 = (h0 >= 1.0), s1 = (h1 >= 1.0), s2 = (h2v >= 1.0), s3 = (h3v >= 1.0);
        v00 = s0 ? 0.0 : h0; v01 = s1 ? 0.0 : h1;
        v10 = s2 ? 0.0 : h2v; v11 = s3 ? 0.0 : h3v;
        z[(size_t)(t * BATCH + b) * FC1_IN + ci * 49 + w49] = (u8)(s0 | s1 | s2 | s3);
    }
}

// ---------------------------------------------------------------------------
// K4w: quantize fc1 weights to 6 signed base-128 digits at scale 2^40.
// Layout Wd1[d][kb][o][32] i8 -> coalesced B-fragment loads.
// ---------------------------------------------------------------------------
__global__ __launch_bounds__(256) void k4w_quant(
    const float* __restrict__ fw, s8* __restrict__ Wd1)
{
    int g = blockIdx.x * 256 + threadIdx.x;   // kb*2048 + o
    if (g >= FC1_KB * FC1_OUT) return;
    int o = g & 2047, kb = g >> 11;

    u32 tmp[FC1_DIGITS][8];
#pragma unroll
    for (int d = 0; d < FC1_DIGITS; ++d)
#pragma unroll
        for (int q = 0; q < 8; ++q) tmp[d][q] = 0;

#pragma unroll
    for (int j = 0; j < 32; ++j) {
        double wd = (double)fw[(size_t)o * FC1_IN + kb * 32 + j] * FC1_SCALE;
        long r = (long)llrint(wd);
#pragma unroll
        for (int d = 0; d < FC1_DIGITS; ++d) {
            int dg = (int)(r & 127);
            if (dg >= 64) dg -= 128;
            r = (r - (long)dg) >> 7;
            tmp[d][j >> 2] |= (u32)(dg & 255) << ((j & 3) * 8);
        }
    }
#pragma unroll
    for (int d = 0; d < FC1_DIGITS; ++d) {
        u32* dst = (u32*)(Wd1 + (((size_t)d * FC1_KB + kb) * FC1_OUT + o) * 32);
        *(uint4*)dst       = make_uint4(tmp[d][0], tmp[d][1], tmp[d][2], tmp[d][3]);
        *(uint4*)(dst + 4) = make_uint4(tmp[d][4], tmp[d][5], tmp[d][6], tmp[d][7]);
    }
}

// ---------------------------------------------------------------------------
// K4: fc1 via exact fixed-point i8 MFMA GEMM. M=1024(tb) N=2048(o) K=6272.
// Block: 256 thr = 4 waves, tile 64(m) x 128(n); wave: 32m x 64n (2 subtiles).
// Digit-outer loop, i64 carry recombination; h3 = carry * 2^-40 (f64 exact).
// XCD-swizzle: blocks sharing an N-column colocate on one XCD.
// ---------------------------------------------------------------------------
__global__ __launch_bounds__(256) void k4_fc1_i8(
    const u8* __restrict__ z, const s8* __restrict__ Wd1,
    double* __restrict__ h3)
{
    int bx = blockIdx.x;              // 256 blocks
    int xcd = bx & 7, idx = bx >> 3;
    int ntile = xcd * 2 + (idx >> 4); // 0..15
    int mtile = idx & 15;             // 0..15

    int tid = threadIdx.x;
    int lane = tid & 63;
    int lane32 = lane & 31;
    int khalf = (lane >> 5) << 4;
    int w = tid >> 6;
    int wm = w >> 1, wn = w & 1;

    int tb0 = mtile * 64 + wm * 32;
    int o0  = ntile * 128 + wn * 64;

    const u8* za = z + (size_t)(tb0 + lane32) * FC1_IN + khalf;

    long carry0[16], carry1[16];
#pragma unroll
    for (int r = 0; r < 16; ++r) { carry0[r] = 0; carry1[r] = 0; }

#pragma unroll 1
    for (int d = 0; d < FC1_DIGITS; ++d) {
        v16i a0, a1;
#pragma unroll
        for (int r = 0; r < 16; ++r) { a0[r] = 0; a1[r] = 0; }

        const s8* bp = Wd1 + ((size_t)d * FC1_KB * FC1_OUT) * 32
                           + ((size_t)o0 + lane32) * 32 + khalf;
#pragma unroll 4
        for (int kb = 0; kb < FC1_KB; ++kb) {
            v4i A  = *(const v4i*)(za + kb * 32);
            v4i B0 = *(const v4i*)(bp + (size_t)kb * FC1_OUT * 32);
            v4i B1 = *(const v4i*)(bp + (size_t)kb * FC1_OUT * 32 + 32 * 32);
            a0 = __builtin_amdgcn_mfma_i32_32x32x32_i8(A, B0, a0, 0, 0, 0);
            a1 = __builtin_amdgcn_mfma_i32_32x32x32_i8(A, B1, a1, 0, 0, 0);
        }
        int sh = 7 * d;
#pragma unroll
        for (int r = 0; r < 16; ++r) {
            carry0[r] += ((long)a0[r]) << sh;
            carry1[r] += ((long)a1[r]) << sh;
        }
    }

    int rhi = (lane >> 5) * 4;
#pragma unroll
    for (int r = 0; r < 16; ++r) {
        int row = (r & 3) + 8 * (r >> 2) + rhi;
        size_t base = (size_t)(tb0 + row) * FC1_OUT;
        h3[base + o0 + lane32]      = (double)carry0[r] * FC1_INVSCALE;
        h3[base + o0 + 32 + lane32] = (double)carry1[r] * FC1_INVSCALE;
    }
}

// ---------------------------------------------------------------------------
// K5: IF over T on h3 -> s3[tb][2048] u8
// ---------------------------------------------------------------------------
__global__ __launch_bounds__(256) void k5_if3(
    const double* __restrict__ h3, u8* __restrict__ s3)
{
    int g = blockIdx.x * 256 + threadIdx.x;
    int b = g >> 11;
    int o = g & 2047;
    double v = 0.0;
#pragma unroll
    for (int t = 0; t < 8; ++t) {
        double h = v + h3[(size_t)(t * BATCH + b) * FC1_OUT + o];
        int s = (h >= 1.0);
        v = s ? 0.0 : h;
        s3[(size_t)(t * BATCH + b) * FC1_OUT + o] = (u8)s;
    }
}

// ---------------------------------------------------------------------------
// K6: fc2  h4[tb][16(10 used)] = sum_i s3[tb][i]*fw2[o][i], f64, wave-reduced
// ---------------------------------------------------------------------------
__global__ __launch_bounds__(64) void k6_fc2(
    const u8* __restrict__ s3, const float* __restrict__ fw2,
    double* __restrict__ h4)
{
    int tb = blockIdx.x;
    int lane = threadIdx.x;
    double acc[10];
#pragma unroll
    for (int o = 0; o < 10; ++o) acc[o] = 0.0;

    for (int k = 0; k < 32; ++k) {
        int i = k * 64 + lane;
        double zd = (double)s3[(size_t)tb * FC1_OUT + i];
#pragma unroll
        for (int o = 0; o < 10; ++o)
            acc[o] += zd * (double)fw2[o * FC1_OUT + i];
    }
#pragma unroll
    for (int o = 0; o < 10; ++o) {
#pragma unroll
        for (int off = 32; off >= 1; off >>= 1)
            acc[o] += __shfl_down(acc[o], off);
    }
    if (lane == 0) {
#pragma unroll
        for (int o = 0; o < 10; ++o) h4[(size_t)tb * 16 + o] = acc[o];
    }
}

// ---------------------------------------------------------------------------
// K7: IF over T on h4 + mean -> out[b][10] f32
// ---------------------------------------------------------------------------
__global__ __launch_bounds__(256) void k7_if4_mean(
    const double* __restrict__ h4, float* __restrict__ out)
{
    int g = blockIdx.x * 256 + threadIdx.x;
    if (g >= BATCH * FC2_OUT) return;
    int b = g / 10;
    int o = g - b * 10;
    double v = 0.0; int cnt = 0;
#pragma unroll
    for (int t = 0; t < 8; ++t) {
        double h = v + h4[(size_t)(t * BATCH + b) * 16 + o];
        int s = (h >= 1.0);
        cnt += s;
        v = s ? 0.0 : h;
    }
    out[b * 10 + o] = (float)cnt * 0.125f;
}

// ---------------------------------------------------------------------------
extern "C" void kernel_launch(void* const* d_in, const int* in_sizes, int n_in,
                              void* d_out, int out_size, void* d_ws, size_t ws_size,
                              hipStream_t stream)
{
    const float* x   = (const float*)d_in[0];
    const float* w1  = (const float*)d_in[1];
    const float* g1  = (const float*)d_in[2];
    const float* b1  = (const float*)d_in[3];
    const float* m1  = (const float*)d_in[4];
    const float* v1  = (const float*)d_in[5];
    const float* w2  = (const float*)d_in[6];
    const float* g2  = (const float*)d_in[7];
    const float* b2  = (const float*)d_in[8];
    const float* m2  = (const float*)d_in[9];
    const float* v2  = (const float*)d_in[10];
    const float* fw1 = (const float*)d_in[11];
    const float* fw2 = (const float*)d_in[12];
    float* out = (float*)d_out;

    char* ws = (char*)d_ws;
    size_t off = 0;
    auto alloc = [&](size_t sz) { size_t o = off; off = (off + sz + 255) & ~(size_t)255; return o; };

    size_t o_p1 = alloc((size_t)TSTEPS * BATCH * CH * 8 * 4);   // 4 MB
    size_t o_z  = alloc((size_t)TB * FC1_IN);                   // 6.4 MB
    size_t o_h3 = alloc((size_t)TB * FC1_OUT * 8);              // 16.8 MB
    size_t o_s3 = alloc((size_t)TB * FC1_OUT);                  // 2.1 MB
    size_t o_h4 = alloc((size_t)TB * 16 * 8);                   // 128 KB
    size_t o_wd = alloc((size_t)W2_DIGITS * 9 * CH * CH);       // 737 KB
    size_t o_h2 = off;                                          // shared region:
    // h2T (205.5 MB f64) lives k2->k3; Wd1 (77 MB) is written AFTER k3 and
    // aliases the same region (fits even under the 102.8 MB f32 fallback).
    size_t h2_f64_bytes = (size_t)TB * CH * NPIX2 * 8;
    int is64 = (off + h2_f64_bytes <= ws_size) ? 1 : 0;

    u32*    p1bits = (u32*)(ws + o_p1);
    u8*     z      = (u8*)(ws + o_z);
    double* h3     = (double*)(ws + o_h3);
    u8*     s3     = (u8*)(ws + o_s3);
    double* h4     = (double*)(ws + o_h4);
    s8*     Wd     = (s8*)(ws + o_wd);
    void*   h2T    = (void*)(ws + o_h2);
    s8*     Wd1    = (s8*)(ws + o_h2);   // alias, disjoint lifetime

    k2w_quant<<<dim3((CH * CH + 255) / 256), dim3(256), 0, stream>>>(w2, Wd);

    k1_conv1_if_pool<<<dim3(BATCH * CH), dim3(256), 0, stream>>>(
        x, w1, g1, b1, m1, v1, p1bits);

    k2_conv2_i8<<<dim3(TB), dim3(512), 0, stream>>>(
        p1bits, Wd, g2, b2, m2, v2, h2T, is64);

    k3_if2_pool<<<dim3(BATCH * 49 * CH / 256), dim3(256), 0, stream>>>(
        h2T, z, is64);

    k4w_quant<<<dim3((FC1_KB * FC1_OUT + 255) / 256), dim3(256), 0, stream>>>(
        fw1, Wd1);

    k4_fc1_i8<<<dim3(256), dim3(256), 0, stream>>>(z, Wd1, h3);

    k5_if3<<<dim3(BATCH * FC1_OUT / 256), dim3(256), 0, stream>>>(h3, s3);

    k6_fc2<<<dim3(TB), dim3(64), 0, stream>>>(s3, fw2, h4);

    k7_if4_mean<<<dim3((BATCH * FC2_OUT + 255) / 256), dim3(256), 0, stream>>>(h4, out);
}

// Round 4
// 706.266 us; speedup vs baseline: 3.5763x; 2.0597x over previous
//
#include <hip/hip_runtime.h>
#include <stdint.h>

typedef unsigned int u32;
typedef unsigned long long u64;
typedef unsigned char u8;
typedef signed char s8;
typedef int v4i __attribute__((ext_vector_type(4)));
typedef int v16i __attribute__((ext_vector_type(16)));

#define TSTEPS 8
#define BATCH 128
#define CH 128
#define NPIX1 784   // 28*28
#define NPIX2 196   // 14*14
#define TB 1024     // TSTEPS*BATCH
#define FC1_OUT 2048
#define FC1_IN 6272 // 128*49
#define FC2_OUT 10

#define W2_DIGITS 5
#define W2_SCALE 34359738368.0              // 2^35
#define W2_INVSCALE 2.9103830456733704e-11  // 2^-35

#define FC1_DIGITS 6
#define FC1_KB 196                          // 6272/32
#define FC1_SCALE 1099511627776.0           // 2^40
#define FC1_INVSCALE 9.094947017729282e-13  // 2^-40

typedef __attribute__((address_space(3))) u32 lds_u32;
typedef const __attribute__((address_space(1))) u32 glb_u32;
#define GLOAD16(G, L) __builtin_amdgcn_global_load_lds((glb_u32*)(G), (lds_u32*)(L), 16, 0, 0)

// ---------------------------------------------------------------------------
// K1: conv1(1->128,3x3,SAME) + bn1 + IF over T=8 (constant input) + 2x2 maxpool
// output: p1bits[t][b][ci][8 u32]  (bit p = pooled spike at 14x14 pixel p)
// ---------------------------------------------------------------------------
__global__ __launch_bounds__(256) void k1_conv1_if_pool(
    const float* __restrict__ x, const float* __restrict__ w1,
    const float* __restrict__ g1, const float* __restrict__ b1,
    const float* __restrict__ m1, const float* __restrict__ v1,
    u32* __restrict__ p1bits)
{
    int blk = blockIdx.x;
    int b  = blk >> 7;
    int co = blk & 127;
    int tid = threadIdx.x;

    __shared__ u32 sbyte[NPIX1];

    double wk[9];
#pragma unroll
    for (int k = 0; k < 9; ++k) wk[k] = (double)w1[co * 9 + k];
    double inv  = (double)g1[co] / sqrt((double)v1[co] + 1e-5);
    double beta = (double)b1[co] - (double)m1[co] * inv;

    const float* xb = x + (size_t)b * NPIX1;

    for (int p = tid; p < NPIX1; p += 256) {
        int y  = p / 28;
        int xx = p - y * 28;
        double acc = 0.0;
#pragma unroll
        for (int dy = 0; dy < 3; ++dy) {
            int iy = y + dy - 1;
#pragma unroll
            for (int dx = 0; dx < 3; ++dx) {
                int ix = xx + dx - 1;
                if (iy >= 0 && iy < 28 && ix >= 0 && ix < 28)
                    acc += (double)xb[iy * 28 + ix] * wk[dy * 3 + dx];
            }
        }
        double yv = acc * inv + beta;
        double v = 0.0; u32 byte = 0;
#pragma unroll
        for (int t = 0; t < 8; ++t) {
            double h = v + yv;
            int s = (h >= 1.0);
            byte |= (u32)s << t;
            v = s ? 0.0 : h;
        }
        sbyte[p] = byte;
    }
    __syncthreads();

    u32 pooled = 0;
    if (tid < NPIX2) {
        int y14 = tid / 14;
        int x14 = tid - y14 * 14;
        int p0 = (2 * y14) * 28 + 2 * x14;
        pooled = sbyte[p0] | sbyte[p0 + 1] | sbyte[p0 + 28] | sbyte[p0 + 29];
    }

    int lane = tid & 63;
    int wv   = tid >> 6;
    u32 val = 0;
#pragma unroll
    for (int t = 0; t < 8; ++t) {
        u64 m = __ballot((pooled >> t) & 1);
        u32 piece = (lane & 1) ? (u32)(m >> 32) : (u32)m;
        if ((lane >> 1) == t) val = piece;
    }
    if (lane < 16) {
        int t = lane >> 1, half = lane & 1;
        p1bits[((size_t)(t * BATCH + b) * CH + co) * 8 + wv * 2 + half] = val;
    }
}

// ---------------------------------------------------------------------------
// K2w: quantize conv2 weights to 5 signed base-128 digits at scale 2^35.
// Fragment-order layout: Bt[(((d*9+tap)*4+ks)*4+Nt)*1024 + l*16 + bp]
//   l = (co&31) | (((ci>>4)&1)<<5), Nt = co>>5, ks = ci>>5, bp = ci&15.
// ---------------------------------------------------------------------------
__global__ __launch_bounds__(256) void k2w_quant(
    const float* __restrict__ w2, s8* __restrict__ Bt)
{
    int g = blockIdx.x * 256 + threadIdx.x;   // co*128+ci
    if (g >= CH * CH) return;
    int co = g >> 7, ci = g & 127;
    int ks = ci >> 5, rem = ci & 31, half = rem >> 4, bp = rem & 15;
    int l = (co & 31) | (half << 5);
    int Nt = co >> 5;
#pragma unroll
    for (int k = 0; k < 9; ++k) {
        double wd = (double)w2[(size_t)g * 9 + k] * W2_SCALE;
        long r = (long)llrint(wd);
#pragma unroll
        for (int d = 0; d < W2_DIGITS; ++d) {
            int dg = (int)(r & 127);
            if (dg >= 64) dg -= 128;
            r = (r - (long)dg) >> 7;
            Bt[((size_t)(((d * 9 + k) * 4 + ks) * 4 + Nt)) * 1024 + l * 16 + bp] = (s8)dg;
        }
    }
}

// ---------------------------------------------------------------------------
// K2: conv2 via exact fixed-point i8 MFMA implicit GEMM, LDS-staged B.
// Block = one (t,b), 1024 thr = 16 waves: wave = (Mtile 0..7, co-half 0..1).
// 20 phases (5 digits x 4 ks); per phase: stage next B slab (36 KB, 9tapx4Nt
// fragment-order) via global_load_lds, compute 9 taps x 2 Nt MFMAs.
// ---------------------------------------------------------------------------
__global__ __launch_bounds__(1024, 1) void k2_conv2_i8(
    const u32* __restrict__ p1bits, const s8* __restrict__ Bt,
    const float* __restrict__ g2, const float* __restrict__ bb2,
    const float* __restrict__ m2, const float* __restrict__ v2,
    void* __restrict__ h2T, int is64)
{
    int tb = blockIdx.x;
    int tid = threadIdx.x;
    int lane = tid & 63;
    int lane32 = lane & 31;
    int khalf = (lane >> 5) << 4;
    int wv = __builtin_amdgcn_readfirstlane(tid >> 6);  // 0..15
    int mt = wv >> 1;        // M tile: pixels mt*32..+31
    int ch2 = (wv & 1) * 2;  // Nt pair base: co-half

    __shared__ u8 sp[32768];      // spikes [16x16 halo rows][128 ci], swizzled
    __shared__ u8 bbuf[2 * 36864];

    uint4* sp16 = (uint4*)sp;
#pragma unroll
    for (int q = 0; q < 2; ++q) sp16[tid + q * 1024] = make_uint4(0u, 0u, 0u, 0u);
    __syncthreads();

    // stage spikes: bit -> i8, halo border stays 0
    for (int c = tid; c < NPIX2 * 8; c += 1024) {
        int p = c >> 3, cg = c & 7;
        int ci0 = cg * 16;
        int py = (p * 2341) >> 15;
        int px = p - py * 14;
        int row = (py + 1) * 16 + (px + 1);
        int wi = p >> 5, bit = p & 31;
        const u32* bp = p1bits + ((size_t)tb * CH + ci0) * 8 + wi;
        u32 wd0 = 0, wd1 = 0, wd2 = 0, wd3 = 0;
#pragma unroll
        for (int j = 0; j < 4; ++j) {
            wd0 |= ((bp[(j     ) * 8] >> bit) & 1u) << (j * 8);
            wd1 |= ((bp[(j +  4) * 8] >> bit) & 1u) << (j * 8);
            wd2 |= ((bp[(j +  8) * 8] >> bit) & 1u) << (j * 8);
            wd3 |= ((bp[(j + 12) * 8] >> bit) & 1u) << (j * 8);
        }
        int addr = (row * 128 + ci0) ^ ((row & 7) << 4);
        *(uint4*)(sp + addr) = make_uint4(wd0, wd1, wd2, wd3);
    }

    // stage phase 0 B slab
    {
        int d = 0, ks = 0;
        for (int i = wv; i < 36; i += 16) {
            int tap = i >> 2, Nt = i & 3;
            const s8* src = Bt + ((size_t)(((d * 9 + tap) * 4 + ks) * 4 + Nt)) * 1024 + lane * 16;
            GLOAD16(src, bbuf + i * 1024);
        }
    }
    __syncthreads();

    int p  = mt * 32 + lane32;
    int pe = (p < NPIX2) ? p : (NPIX2 - 1);
    int py = (pe * 2341) >> 15;
    int px = pe - py * 14;
    int rb = py * 16 + px;

    long carry0[16], carry1[16];
#pragma unroll
    for (int r = 0; r < 16; ++r) { carry0[r] = 0; carry1[r] = 0; }

    v16i a0, a1;
#pragma unroll
    for (int r = 0; r < 16; ++r) { a0[r] = 0; a1[r] = 0; }

#pragma unroll 1
    for (int ph = 0; ph < 20; ++ph) {
        int buf = ph & 1;
        // stage next phase's B slab into the other buffer
        if (ph + 1 < 20) {
            int d1 = (ph + 1) >> 2, ks1 = (ph + 1) & 3;
            for (int i = wv; i < 36; i += 16) {
                int tap = i >> 2, Nt = i & 3;
                const s8* src = Bt + ((size_t)(((d1 * 9 + tap) * 4 + ks1) * 4 + Nt)) * 1024 + lane * 16;
                GLOAD16(src, bbuf + (buf ^ 1) * 36864 + i * 1024);
            }
        }
        // compute current phase
        {
            int ks = ph & 3;
            const u8* bb = bbuf + buf * 36864;
#pragma unroll
            for (int tap = 0; tap < 9; ++tap) {
                int dy = tap / 3, dx = tap - (tap / 3) * 3;
                int rowidx = rb + dy * 16 + dx;
                int swz = (rowidx & 7) << 4;
                v4i A  = *(const v4i*)(sp + ((rowidx * 128 + ks * 32 + khalf) ^ swz));
                v4i B0 = *(const v4i*)(bb + (tap * 4 + ch2    ) * 1024 + lane * 16);
                v4i B1 = *(const v4i*)(bb + (tap * 4 + ch2 + 1) * 1024 + lane * 16);
                a0 = __builtin_amdgcn_mfma_i32_32x32x32_i8(A, B0, a0, 0, 0, 0);
                a1 = __builtin_amdgcn_mfma_i32_32x32x32_i8(A, B1, a1, 0, 0, 0);
            }
        }
        if ((ph & 3) == 3) {  // end of digit
            int sh = 7 * (ph >> 2);
#pragma unroll
            for (int r = 0; r < 16; ++r) {
                carry0[r] += ((long)a0[r]) << sh;
                carry1[r] += ((long)a1[r]) << sh;
                a0[r] = 0; a1[r] = 0;
            }
        }
        __syncthreads();
    }

    int rhi = (lane >> 5) * 4;
#define EPILOGUE(NT, CARR)                                                    \
    {                                                                         \
        int co = (NT) * 32 + lane32;                                          \
        double inv  = (double)g2[co] / sqrt((double)v2[co] + 1e-5);           \
        double beta = (double)bb2[co] - (double)m2[co] * inv;                 \
        _Pragma("unroll")                                                     \
        for (int r = 0; r < 16; ++r) {                                        \
            int pix = mt * 32 + (r & 3) + 8 * (r >> 2) + rhi;                 \
            if (pix < NPIX2) {                                                \
                double h = (double)CARR[r] * W2_INVSCALE * inv + beta;        \
                size_t idx = ((size_t)tb * NPIX2 + pix) * CH + co;            \
                if (is64) ((double*)h2T)[idx] = h;                            \
                else      ((float*)h2T)[idx] = (float)h;                      \
            }                                                                 \
        }                                                                     \
    }
    EPILOGUE(ch2,     carry0)
    EPILOGUE(ch2 + 1, carry1)
#undef EPILOGUE
}

// ---------------------------------------------------------------------------
// K3: IF over T on h2T + 2x2 maxpool -> z2[kb][tb][32] u8 (0/1), kb = i>>5
// ---------------------------------------------------------------------------
__global__ __launch_bounds__(256) void k3_if2_pool(
    const void* __restrict__ h2T, u8* __restrict__ z2, int is64)
{
    int g = blockIdx.x * 256 + threadIdx.x;   // 128*49*128 = 802816
    int ci = g & 127;
    int rest = g >> 7;
    int b = rest / 49;
    int w49 = rest - b * 49;
    int wy = w49 / 7, wx = w49 - wy * 7;
    int pix = (2 * wy) * 14 + 2 * wx;
    int i = ci * 49 + w49;                    // fc1 input index
    size_t zoff = ((size_t)(i >> 5) * TB) * 32 + (i & 31);

    double v00 = 0, v01 = 0, v10 = 0, v11 = 0;
#pragma unroll
    for (int t = 0; t < 8; ++t) {
        size_t base = ((size_t)(t * BATCH + b) * NPIX2 + pix) * CH + ci;
        double a00, a01, a10, a11;
        if (is64) {
            const double* hp = (const double*)h2T;
            a00 = hp[base];            a01 = hp[base + CH];
            a10 = hp[base + 14 * CH];  a11 = hp[base + 15 * CH];
        } else {
            const float* hp = (const float*)h2T;
            a00 = (double)hp[base];           a01 = (double)hp[base + CH];
            a10 = (double)hp[base + 14 * CH]; a11 = (double)hp[base + 15 * CH];
        }
        double h0 = v00 + a00, h1 = v01 + a01, h2v = v10 + a10, h3v = v11 + a11;
        int s0 = (h0 >= 1.0), s1 = (h1 >= 1.0), s2 = (h2v >= 1.0), s3 = (h3v >= 1.0);
        v00 = s0 ? 0.0 : h0; v01 = s1 ? 0.0 : h1;
        v10 = s2 ? 0.0 : h2v; v11 = s3 ? 0.0 : h3v;
        z2[zoff + (size_t)(t * BATCH + b) * 32] = (u8)(s0 | s1 | s2 | s3);
    }
}

// ---------------------------------------------------------------------------
// K4w: quantize fc1 weights to 6 signed base-128 digits at scale 2^40.
// Layout Wd1[d][kb][o][32] i8.
// ---------------------------------------------------------------------------
__global__ __launch_bounds__(256) void k4w_quant(
    const float* __restrict__ fw, s8* __restrict__ Wd1)
{
    int g = blockIdx.x * 256 + threadIdx.x;   // kb*2048 + o
    if (g >= FC1_KB * FC1_OUT) return;
    int o = g & 2047, kb = g >> 11;

    u32 tmp[FC1_DIGITS][8];
#pragma unroll
    for (int d = 0; d < FC1_DIGITS; ++d)
#pragma unroll
        for (int q = 0; q < 8; ++q) tmp[d][q] = 0;

#pragma unroll
    for (int j = 0; j < 32; ++j) {
        double wd = (double)fw[(size_t)o * FC1_IN + kb * 32 + j] * FC1_SCALE;
        long r = (long)llrint(wd);
#pragma unroll
        for (int d = 0; d < FC1_DIGITS; ++d) {
            int dg = (int)(r & 127);
            if (dg >= 64) dg -= 128;
            r = (r - (long)dg) >> 7;
            tmp[d][j >> 2] |= (u32)(dg & 255) << ((j & 3) * 8);
        }
    }
#pragma unroll
    for (int d = 0; d < FC1_DIGITS; ++d) {
        u32* dst = (u32*)(Wd1 + (((size_t)d * FC1_KB + kb) * FC1_OUT + o) * 32);
        *(uint4*)dst       = make_uint4(tmp[d][0], tmp[d][1], tmp[d][2], tmp[d][3]);
        *(uint4*)(dst + 4) = make_uint4(tmp[d][4], tmp[d][5], tmp[d][6], tmp[d][7]);
    }
}

// ---------------------------------------------------------------------------
// K4: fc1 via exact fixed-point i8 MFMA GEMM, LDS-staged A and B.
// M=1024(tb) N=2048(o) K=6272. Block 64tb x 128o, 4 waves (wm,wn).
// 150 phases = 6 digits x 25 K-steps (8 kb each, last 4). Per phase: stage
// next A(16KB)+B(32KB) fragment-order slabs via global_load_lds, compute.
// ---------------------------------------------------------------------------
__global__ __launch_bounds__(256, 1) void k4_fc1_i8(
    const u8* __restrict__ z2, const s8* __restrict__ Wd1,
    double* __restrict__ h3)
{
    __shared__ u8 stg[2 * 49152];   // [buf][A 16KB | B 32KB]

    int bx = blockIdx.x;              // 256 blocks
    int xcd = bx & 7, idx = bx >> 3;
    int ntile = xcd * 2 + (idx >> 4); // 0..15
    int mtile = idx & 15;             // 0..15

    int tid = threadIdx.x;
    int lane = tid & 63;
    int lane32 = lane & 31;
    int wv = __builtin_amdgcn_readfirstlane(tid >> 6);
    int wm = wv >> 1, wn = wv & 1;

    int tb0 = mtile * 64;
    int o0  = ntile * 128;

    long carry0[16], carry1[16];
#pragma unroll
    for (int r = 0; r < 16; ++r) { carry0[r] = 0; carry1[r] = 0; }
    v16i a0, a1;
#pragma unroll
    for (int r = 0; r < 16; ++r) { a0[r] = 0; a1[r] = 0; }

    // stage phase q into buffer buf
    auto stage = [&](int q, int buf) {
        int d = q / 25, s = q - d * 25;
        for (int i = wv; i < 48; i += 4) {
            if (i < 16) {
                int kb = i >> 1, wms = i & 1;
                int kbg = s * 8 + kb;
                if (kbg < FC1_KB) {
                    const u8* src = z2 + ((size_t)kbg * TB + tb0 + wms * 32 + lane32) * 32
                                       + (lane >> 5) * 16;
                    GLOAD16(src, stg + buf * 49152 + i * 1024);
                }
            } else {
                int j = i - 16;
                int kb = j >> 2, Nt = j & 3;
                int kbg = s * 8 + kb;
                if (kbg < FC1_KB) {
                    const s8* src = Wd1 + (((size_t)d * FC1_KB + kbg) * FC1_OUT
                                           + o0 + Nt * 32 + lane32) * 32
                                        + (lane >> 5) * 16;
                    GLOAD16(src, stg + buf * 49152 + 16384 + j * 1024);
                }
            }
        }
    };

    stage(0, 0);
    __syncthreads();

#pragma unroll 1
    for (int q = 0; q < FC1_DIGITS * 25; ++q) {
        int buf = q & 1;
        if (q + 1 < FC1_DIGITS * 25) stage(q + 1, buf ^ 1);

        int d = q / 25, s = q - d * 25;
        int kbn = (s == 24) ? 4 : 8;
        const u8* A_ = stg + buf * 49152;
        const u8* B_ = A_ + 16384;
#pragma unroll 1
        for (int kb = 0; kb < kbn; ++kb) {
            v4i A  = *(const v4i*)(A_ + (kb * 2 + wm) * 1024 + lane * 16);
            v4i B0 = *(const v4i*)(B_ + (kb * 4 + wn * 2) * 1024 + lane * 16);
            v4i B1 = *(const v4i*)(B_ + (kb * 4 + wn * 2 + 1) * 1024 + lane * 16);
            a0 = __builtin_amdgcn_mfma_i32_32x32x32_i8(A, B0, a0, 0, 0, 0);
            a1 = __builtin_amdgcn_mfma_i32_32x32x32_i8(A, B1, a1, 0, 0, 0);
        }
        if (s == 24) {
            int sh = 7 * d;
#pragma unroll
            for (int r = 0; r < 16; ++r) {
                carry0[r] += ((long)a0[r]) << sh;
                carry1[r] += ((long)a1[r]) << sh;
                a0[r] = 0; a1[r] = 0;
            }
        }
        __syncthreads();
    }

    int rhi = (lane >> 5) * 4;
    int ob = o0 + wn * 64;
#pragma unroll
    for (int r = 0; r < 16; ++r) {
        int row = (r & 3) + 8 * (r >> 2) + rhi;
        size_t base = (size_t)(tb0 + wm * 32 + row) * FC1_OUT;
        h3[base + ob + lane32]      = (double)carry0[r] * FC1_INVSCALE;
        h3[base + ob + 32 + lane32] = (double)carry1[r] * FC1_INVSCALE;
    }
}

// ---------------------------------------------------------------------------
// K5: IF over T on h3 -> s3[tb][2048] u8
// ---------------------------------------------------------------------------
__global__ __launch_bounds__(256) void k5_if3(
    const double* __restrict__ h3, u8* __restrict__ s3)
{
    int g = blockIdx.x * 256 + threadIdx.x;
    int b = g >> 11;
    int o = g & 2047;
    double v = 0.0;
#pragma unroll
    for (int t = 0; t < 8; ++t) {
        double h = v + h3[(size_t)(t * BATCH + b) * FC1_OUT + o];
        int s = (h >= 1.0);
        v = s ? 0.0 : h;
        s3[(size_t)(t * BATCH + b) * FC1_OUT + o] = (u8)s;
    }
}

// ---------------------------------------------------------------------------
// K6: fc2  h4[tb][16(10 used)] = sum_i s3[tb][i]*fw2[o][i], f64, wave-reduced
// ---------------------------------------------------------------------------
__global__ __launch_bounds__(64) void k6_fc2(
    const u8* __restrict__ s3, const float* __restrict__ fw2,
    double* __restrict__ h4)
{
    int tb = blockIdx.x;
    int lane = threadIdx.x;
    double acc[10];
#pragma unroll
    for (int o = 0; o < 10; ++o) acc[o] = 0.0;

    for (int k = 0; k < 32; ++k) {
        int i = k * 64 + lane;
        double zd = (double)s3[(size_t)tb * FC1_OUT + i];
#pragma unroll
        for (int o = 0; o < 10; ++o)
            acc[o] += zd * (double)fw2[o * FC1_OUT + i];
    }
#pragma unroll
    for (int o = 0; o < 10; ++o) {
#pragma unroll
        for (int off = 32; off >= 1; off >>= 1)
            acc[o] += __shfl_down(acc[o], off);
    }
    if (lane == 0) {
#pragma unroll
        for (int o = 0; o < 10; ++o) h4[(size_t)tb * 16 + o] = acc[o];
    }
}

// ---------------------------------------------------------------------------
// K7: IF over T on h4 + mean -> out[b][10] f32
// ---------------------------------------------------------------------------
__global__ __launch_bounds__(256) void k7_if4_mean(
    const double* __restrict__ h4, float* __restrict__ out)
{
    int g = blockIdx.x * 256 + threadIdx.x;
    if (g >= BATCH * FC2_OUT) return;
    int b = g / 10;
    int o = g - b * 10;
    double v = 0.0; int cnt = 0;
#pragma unroll
    for (int t = 0; t < 8; ++t) {
        double h = v + h4[(size_t)(t * BATCH + b) * 16 + o];
        int s = (h >= 1.0);
        cnt += s;
        v = s ? 0.0 : h;
    }
    out[b * 10 + o] = (float)cnt * 0.125f;
}

// ---------------------------------------------------------------------------
extern "C" void kernel_launch(void* const* d_in, const int* in_sizes, int n_in,
                              void* d_out, int out_size, void* d_ws, size_t ws_size,
                              hipStream_t stream)
{
    const float* x   = (const float*)d_in[0];
    const float* w1  = (const float*)d_in[1];
    const float* g1  = (const float*)d_in[2];
    const float* b1  = (const float*)d_in[3];
    const float* m1  = (const float*)d_in[4];
    const float* v1  = (const float*)d_in[5];
    const float* w2  = (const float*)d_in[6];
    const float* g2  = (const float*)d_in[7];
    const float* b2  = (const float*)d_in[8];
    const float* m2  = (const float*)d_in[9];
    const float* v2  = (const float*)d_in[10];
    const float* fw1 = (const float*)d_in[11];
    const float* fw2 = (const float*)d_in[12];
    float* out = (float*)d_out;

    char* ws = (char*)d_ws;
    size_t off = 0;
    auto alloc = [&](size_t sz) { size_t o = off; off = (off + sz + 255) & ~(size_t)255; return o; };

    size_t o_p1 = alloc((size_t)TSTEPS * BATCH * CH * 8 * 4);   // 4 MB
    size_t o_z  = alloc((size_t)TB * FC1_IN);                   // 6.4 MB (z2)
    size_t o_h3 = alloc((size_t)TB * FC1_OUT * 8);              // 16.8 MB
    size_t o_s3 = alloc((size_t)TB * FC1_OUT);                  // 2.1 MB
    size_t o_h4 = alloc((size_t)TB * 16 * 8);                   // 128 KB
    size_t o_wd = alloc((size_t)W2_DIGITS * 9 * CH * CH);       // 737 KB (Bt)
    size_t o_h2 = off;                                          // shared region:
    // h2T (205.5 MB f64) lives k2->k3; Wd1 (77 MB) is written AFTER k3 and
    // aliases the same region.
    size_t h2_f64_bytes = (size_t)TB * CH * NPIX2 * 8;
    int is64 = (off + h2_f64_bytes <= ws_size) ? 1 : 0;

    u32*    p1bits = (u32*)(ws + o_p1);
    u8*     z2     = (u8*)(ws + o_z);
    double* h3     = (double*)(ws + o_h3);
    u8*     s3     = (u8*)(ws + o_s3);
    double* h4     = (double*)(ws + o_h4);
    s8*     Bt     = (s8*)(ws + o_wd);
    void*   h2T    = (void*)(ws + o_h2);
    s8*     Wd1    = (s8*)(ws + o_h2);   // alias, disjoint lifetime

    k2w_quant<<<dim3((CH * CH + 255) / 256), dim3(256), 0, stream>>>(w2, Bt);

    k1_conv1_if_pool<<<dim3(BATCH * CH), dim3(256), 0, stream>>>(
        x, w1, g1, b1, m1, v1, p1bits);

    k2_conv2_i8<<<dim3(TB), dim3(1024), 0, stream>>>(
        p1bits, Bt, g2, b2, m2, v2, h2T, is64);

    k3_if2_pool<<<dim3(BATCH * 49 * CH / 256), dim3(256), 0, stream>>>(
        h2T, z2, is64);

    k4w_quant<<<dim3((FC1_KB * FC1_OUT + 255) / 256), dim3(256), 0, stream>>>(
        fw1, Wd1);

    k4_fc1_i8<<<dim3(256), dim3(256), 0, stream>>>(z2, Wd1, h3);

    k5_if3<<<dim3(BATCH * FC1_OUT / 256), dim3(256), 0, stream>>>(h3, s3);

    k6_fc2<<<dim3(TB), dim3(64), 0, stream>>>(s3, fw2, h4);

    k7_if4_mean<<<dim3((BATCH * FC2_OUT + 255) / 256), dim3(256), 0, stream>>>(h4, out);
}

// Round 5
// 428.480 us; speedup vs baseline: 5.8948x; 1.6483x over previous
//
#include <hip/hip_runtime.h>
#include <stdint.h>

typedef unsigned int u32;
typedef unsigned long long u64;
typedef unsigned char u8;
typedef signed char s8;
typedef int v4i __attribute__((ext_vector_type(4)));
typedef int v16i __attribute__((ext_vector_type(16)));

#define TSTEPS 8
#define BATCH 128
#define CH 128
#define NPIX1 784   // 28*28
#define NPIX2 196   // 14*14
#define TB 1024     // TSTEPS*BATCH
#define FC1_OUT 2048
#define FC1_IN 6272 // 128*49
#define FC2_OUT 10

// conv2: 4 signed base-256 digits, scale 2^32 (|w2|max~0.25 -> |r|<2^31, range 2^31.01)
#define W2_DIGITS 4
#define W2_SCALE 4294967296.0               // 2^32
#define W2_INVSCALE 2.3283064365386963e-10  // 2^-32

// fc1: 5 signed base-256 digits, scale 2^39 (|fw1|max~0.11 -> |r|<2^36, range 2^39)
#define FC1_DIGITS 5
#define FC1_KB 196                          // 6272/32
#define FC1_SCALE 549755813888.0            // 2^39
#define FC1_INVSCALE 1.8189894035458565e-12 // 2^-39

typedef __attribute__((address_space(3))) u32 lds_u32;
typedef const __attribute__((address_space(1))) u32 glb_u32;
#define GLOAD16(G, L) __builtin_amdgcn_global_load_lds((glb_u32*)(G), (lds_u32*)(L), 16, 0, 0)

// ---------------------------------------------------------------------------
// K1: conv1(1->128,3x3,SAME) + bn1 + IF over T=8 (constant input) + 2x2 maxpool
// output: p1bits[t][b][ci][8 u32]  (bit p = pooled spike at 14x14 pixel p)
// ---------------------------------------------------------------------------
__global__ __launch_bounds__(256) void k1_conv1_if_pool(
    const float* __restrict__ x, const float* __restrict__ w1,
    const float* __restrict__ g1, const float* __restrict__ b1,
    const float* __restrict__ m1, const float* __restrict__ v1,
    u32* __restrict__ p1bits)
{
    int blk = blockIdx.x;
    int b  = blk >> 7;
    int co = blk & 127;
    int tid = threadIdx.x;

    __shared__ u32 sbyte[NPIX1];

    double wk[9];
#pragma unroll
    for (int k = 0; k < 9; ++k) wk[k] = (double)w1[co * 9 + k];
    double inv  = (double)g1[co] / sqrt((double)v1[co] + 1e-5);
    double beta = (double)b1[co] - (double)m1[co] * inv;

    const float* xb = x + (size_t)b * NPIX1;

    for (int p = tid; p < NPIX1; p += 256) {
        int y  = p / 28;
        int xx = p - y * 28;
        double acc = 0.0;
#pragma unroll
        for (int dy = 0; dy < 3; ++dy) {
            int iy = y + dy - 1;
#pragma unroll
            for (int dx = 0; dx < 3; ++dx) {
                int ix = xx + dx - 1;
                if (iy >= 0 && iy < 28 && ix >= 0 && ix < 28)
                    acc += (double)xb[iy * 28 + ix] * wk[dy * 3 + dx];
            }
        }
        double yv = acc * inv + beta;
        double v = 0.0; u32 byte = 0;
#pragma unroll
        for (int t = 0; t < 8; ++t) {
            double h = v + yv;
            int s = (h >= 1.0);
            byte |= (u32)s << t;
            v = s ? 0.0 : h;
        }
        sbyte[p] = byte;
    }
    __syncthreads();

    u32 pooled = 0;
    if (tid < NPIX2) {
        int y14 = tid / 14;
        int x14 = tid - y14 * 14;
        int p0 = (2 * y14) * 28 + 2 * x14;
        pooled = sbyte[p0] | sbyte[p0 + 1] | sbyte[p0 + 28] | sbyte[p0 + 29];
    }

    int lane = tid & 63;
    int wv   = tid >> 6;
    u32 val = 0;
#pragma unroll
    for (int t = 0; t < 8; ++t) {
        u64 m = __ballot((pooled >> t) & 1);
        u32 piece = (lane & 1) ? (u32)(m >> 32) : (u32)m;
        if ((lane >> 1) == t) val = piece;
    }
    if (lane < 16) {
        int t = lane >> 1, half = lane & 1;
        p1bits[((size_t)(t * BATCH + b) * CH + co) * 8 + wv * 2 + half] = val;
    }
}

// ---------------------------------------------------------------------------
// K2w: quantize conv2 weights to 4 signed base-256 digits at scale 2^32.
// Fragment-order layout: Bt[(((d*9+tap)*4+ks)*4+Nt)*1024 + l*16 + bp]
// ---------------------------------------------------------------------------
__global__ __launch_bounds__(256) void k2w_quant(
    const float* __restrict__ w2, s8* __restrict__ Bt)
{
    int g = blockIdx.x * 256 + threadIdx.x;   // co*128+ci
    if (g >= CH * CH) return;
    int co = g >> 7, ci = g & 127;
    int ks = ci >> 5, rem = ci & 31, half = rem >> 4, bp = rem & 15;
    int l = (co & 31) | (half << 5);
    int Nt = co >> 5;
#pragma unroll
    for (int k = 0; k < 9; ++k) {
        double wd = (double)w2[(size_t)g * 9 + k] * W2_SCALE;
        long r = (long)llrint(wd);
#pragma unroll
        for (int d = 0; d < W2_DIGITS; ++d) {
            int dg = (int)(((r + 128) & 255) - 128);
            r = (r - (long)dg) >> 8;
            Bt[((size_t)(((d * 9 + k) * 4 + ks) * 4 + Nt)) * 1024 + l * 16 + bp] = (s8)dg;
        }
    }
}

// ---------------------------------------------------------------------------
// K2: conv2 via exact fixed-point i8 MFMA implicit GEMM, LDS-staged B.
// 16 phases (4 digits x 4 ks), double-buffered B slabs.
// ---------------------------------------------------------------------------
__global__ __launch_bounds__(1024, 1) void k2_conv2_i8(
    const u32* __restrict__ p1bits, const s8* __restrict__ Bt,
    const float* __restrict__ g2, const float* __restrict__ bb2,
    const float* __restrict__ m2, const float* __restrict__ v2,
    void* __restrict__ h2T, int is64)
{
    int tb = blockIdx.x;
    int tid = threadIdx.x;
    int lane = tid & 63;
    int lane32 = lane & 31;
    int khalf = (lane >> 5) << 4;
    int wv = __builtin_amdgcn_readfirstlane(tid >> 6);  // 0..15
    int mt = wv >> 1;        // M tile: pixels mt*32..+31
    int ch2 = (wv & 1) * 2;  // Nt pair base: co-half

    __shared__ u8 sp[32768];      // spikes [16x16 halo rows][128 ci], swizzled
    __shared__ u8 bbuf[2 * 36864];

    uint4* sp16 = (uint4*)sp;
#pragma unroll
    for (int q = 0; q < 2; ++q) sp16[tid + q * 1024] = make_uint4(0u, 0u, 0u, 0u);
    __syncthreads();

    // stage spikes: bit -> i8, halo border stays 0
    for (int c = tid; c < NPIX2 * 8; c += 1024) {
        int p = c >> 3, cg = c & 7;
        int ci0 = cg * 16;
        int py = (p * 2341) >> 15;
        int px = p - py * 14;
        int row = (py + 1) * 16 + (px + 1);
        int wi = p >> 5, bit = p & 31;
        const u32* bp = p1bits + ((size_t)tb * CH + ci0) * 8 + wi;
        u32 wd0 = 0, wd1 = 0, wd2 = 0, wd3 = 0;
#pragma unroll
        for (int j = 0; j < 4; ++j) {
            wd0 |= ((bp[(j     ) * 8] >> bit) & 1u) << (j * 8);
            wd1 |= ((bp[(j +  4) * 8] >> bit) & 1u) << (j * 8);
            wd2 |= ((bp[(j +  8) * 8] >> bit) & 1u) << (j * 8);
            wd3 |= ((bp[(j + 12) * 8] >> bit) & 1u) << (j * 8);
        }
        int addr = (row * 128 + ci0) ^ ((row & 7) << 4);
        *(uint4*)(sp + addr) = make_uint4(wd0, wd1, wd2, wd3);
    }

    // stage phase 0 B slab
    {
        for (int i = wv; i < 36; i += 16) {
            int tap = i >> 2, Nt = i & 3;
            const s8* src = Bt + ((size_t)((tap * 4 + 0) * 4 + Nt)) * 1024 + lane * 16;
            GLOAD16(src, bbuf + i * 1024);
        }
    }
    __syncthreads();

    int p  = mt * 32 + lane32;
    int pe = (p < NPIX2) ? p : (NPIX2 - 1);
    int py = (pe * 2341) >> 15;
    int px = pe - py * 14;
    int rb = py * 16 + px;

    long carry0[16], carry1[16];
#pragma unroll
    for (int r = 0; r < 16; ++r) { carry0[r] = 0; carry1[r] = 0; }

    v16i a0, a1;
#pragma unroll
    for (int r = 0; r < 16; ++r) { a0[r] = 0; a1[r] = 0; }

#pragma unroll 1
    for (int ph = 0; ph < W2_DIGITS * 4; ++ph) {
        int buf = ph & 1;
        // stage next phase's B slab into the other buffer
        if (ph + 1 < W2_DIGITS * 4) {
            int d1 = (ph + 1) >> 2, ks1 = (ph + 1) & 3;
            for (int i = wv; i < 36; i += 16) {
                int tap = i >> 2, Nt = i & 3;
                const s8* src = Bt + ((size_t)(((d1 * 9 + tap) * 4 + ks1) * 4 + Nt)) * 1024 + lane * 16;
                GLOAD16(src, bbuf + (buf ^ 1) * 36864 + i * 1024);
            }
        }
        // compute current phase
        {
            int ks = ph & 3;
            const u8* bb = bbuf + buf * 36864;
#pragma unroll
            for (int tap = 0; tap < 9; ++tap) {
                int dy = tap / 3, dx = tap - (tap / 3) * 3;
                int rowidx = rb + dy * 16 + dx;
                int swz = (rowidx & 7) << 4;
                v4i A  = *(const v4i*)(sp + ((rowidx * 128 + ks * 32 + khalf) ^ swz));
                v4i B0 = *(const v4i*)(bb + (tap * 4 + ch2    ) * 1024 + lane * 16);
                v4i B1 = *(const v4i*)(bb + (tap * 4 + ch2 + 1) * 1024 + lane * 16);
                a0 = __builtin_amdgcn_mfma_i32_32x32x32_i8(A, B0, a0, 0, 0, 0);
                a1 = __builtin_amdgcn_mfma_i32_32x32x32_i8(A, B1, a1, 0, 0, 0);
            }
        }
        if ((ph & 3) == 3) {  // end of digit
            int sh = 8 * (ph >> 2);
#pragma unroll
            for (int r = 0; r < 16; ++r) {
                carry0[r] += ((long)a0[r]) << sh;
                carry1[r] += ((long)a1[r]) << sh;
                a0[r] = 0; a1[r] = 0;
            }
        }
        __syncthreads();
    }

    int rhi = (lane >> 5) * 4;
#define EPILOGUE(NT, CARR)                                                    \
    {                                                                         \
        int co = (NT) * 32 + lane32;                                          \
        double inv  = (double)g2[co] / sqrt((double)v2[co] + 1e-5);           \
        double beta = (double)bb2[co] - (double)m2[co] * inv;                 \
        _Pragma("unroll")                                                     \
        for (int r = 0; r < 16; ++r) {                                        \
            int pix = mt * 32 + (r & 3) + 8 * (r >> 2) + rhi;                 \
            if (pix < NPIX2) {                                                \
                double h = (double)CARR[r] * W2_INVSCALE * inv + beta;        \
                size_t idx = ((size_t)tb * NPIX2 + pix) * CH + co;            \
                if (is64) ((double*)h2T)[idx] = h;                            \
                else      ((float*)h2T)[idx] = (float)h;                      \
            }                                                                 \
        }                                                                     \
    }
    EPILOGUE(ch2,     carry0)
    EPILOGUE(ch2 + 1, carry1)
#undef EPILOGUE
}

// ---------------------------------------------------------------------------
// K3: IF over T on h2T + 2x2 maxpool -> z2[kb][tb][32] u8 (0/1), kb = i>>5
// ---------------------------------------------------------------------------
__global__ __launch_bounds__(256) void k3_if2_pool(
    const void* __restrict__ h2T, u8* __restrict__ z2, int is64)
{
    int g = blockIdx.x * 256 + threadIdx.x;   // 128*49*128 = 802816
    int ci = g & 127;
    int rest = g >> 7;
    int b = rest / 49;
    int w49 = rest - b * 49;
    int wy = w49 / 7, wx = w49 - wy * 7;
    int pix = (2 * wy) * 14 + 2 * wx;
    int i = ci * 49 + w49;                    // fc1 input index
    size_t zoff = ((size_t)(i >> 5) * TB) * 32 + (i & 31);

    double v00 = 0, v01 = 0, v10 = 0, v11 = 0;
#pragma unroll
    for (int t = 0; t < 8; ++t) {
        size_t base = ((size_t)(t * BATCH + b) * NPIX2 + pix) * CH + ci;
        double a00, a01, a10, a11;
        if (is64) {
            const double* hp = (const double*)h2T;
            a00 = hp[base];            a01 = hp[base + CH];
            a10 = hp[base + 14 * CH];  a11 = hp[base + 15 * CH];
        } else {
            const float* hp = (const float*)h2T;
            a00 = (double)hp[base];           a01 = (double)hp[base + CH];
            a10 = (double)hp[base + 14 * CH]; a11 = (double)hp[base + 15 * CH];
        }
        double h0 = v00 + a00, h1 = v01 + a01, h2v = v10 + a10, h3v = v11 + a11;
        int s0 = (h0 >= 1.0), s1 = (h1 >= 1.0), s2 = (h2v >= 1.0), s3 = (h3v >= 1.0);
        v00 = s0 ? 0.0 : h0; v01 = s1 ? 0.0 : h1;
        v10 = s2 ? 0.0 : h2v; v11 = s3 ? 0.0 : h3v;
        z2[zoff + (size_t)(t * BATCH + b) * 32] = (u8)(s0 | s1 | s2 | s3);
    }
}

// ---------------------------------------------------------------------------
// K4w: quantize fc1 weights to 5 signed base-256 digits at scale 2^39.
// Layout Wd1[d][kb][o][32] i8.
// ---------------------------------------------------------------------------
__global__ __launch_bounds__(256) void k4w_quant(
    const float* __restrict__ fw, s8* __restrict__ Wd1)
{
    int g = blockIdx.x * 256 + threadIdx.x;   // kb*2048 + o
    if (g >= FC1_KB * FC1_OUT) return;
    int o = g & 2047, kb = g >> 11;

    u32 tmp[FC1_DIGITS][8];
#pragma unroll
    for (int d = 0; d < FC1_DIGITS; ++d)
#pragma unroll
        for (int q = 0; q < 8; ++q) tmp[d][q] = 0;

#pragma unroll
    for (int j = 0; j < 32; ++j) {
        double wd = (double)fw[(size_t)o * FC1_IN + kb * 32 + j] * FC1_SCALE;
        long r = (long)llrint(wd);
#pragma unroll
        for (int d = 0; d < FC1_DIGITS; ++d) {
            int dg = (int)(((r + 128) & 255) - 128);
            r = (r - (long)dg) >> 8;
            tmp[d][j >> 2] |= (u32)(dg & 255) << ((j & 3) * 8);
        }
    }
#pragma unroll
    for (int d = 0; d < FC1_DIGITS; ++d) {
        u32* dst = (u32*)(Wd1 + (((size_t)d * FC1_KB + kb) * FC1_OUT + o) * 32);
        *(uint4*)dst       = make_uint4(tmp[d][0], tmp[d][1], tmp[d][2], tmp[d][3]);
        *(uint4*)(dst + 4) = make_uint4(tmp[d][4], tmp[d][5], tmp[d][6], tmp[d][7]);
    }
}

// ---------------------------------------------------------------------------
// K4: fc1 via i8 MFMA, digit-split across blocks -> i32 partials.
// Grid 640 = 8 XCD x (2 nt x 5 d) x 8 mt. Block 256 thr = 4 waves (2wm x 2wn),
// tile 128tb x 128o, wave tile 64x64 (2x2 subtiles). 49 phases x 4 kb,
// 64 KB LDS double-buffer -> 2 blocks/CU for cross-block latency hiding.
// ---------------------------------------------------------------------------
__global__ __launch_bounds__(256, 2) void k4_fc1_i8(
    const u8* __restrict__ z2, const s8* __restrict__ Wd1,
    int* __restrict__ Hpart)
{
    __shared__ u8 stg[2 * 32768];   // [buf][A 16KB | B 16KB]

    int bx = blockIdx.x;
    int xcd = bx & 7, g = bx >> 3;        // g 0..79
    int ntd = xcd * 10 + (g >> 3);        // 0..79
    int mt = g & 7;
    int nt = ntd / 5, d = ntd - nt * 5;

    int tid = threadIdx.x;
    int lane = tid & 63, lane32 = lane & 31;
    int half16 = (lane >> 5) << 4;
    int wv = __builtin_amdgcn_readfirstlane(tid >> 6);
    int wm = wv >> 1, wn = wv & 1;

    int tb0 = mt * 128, o0 = nt * 128;

    v16i acc00, acc01, acc10, acc11;
#pragma unroll
    for (int r = 0; r < 16; ++r) { acc00[r] = 0; acc01[r] = 0; acc10[r] = 0; acc11[r] = 0; }

    const u8* Abase = z2 + ((size_t)tb0 + lane32) * 32 + half16;
    const s8* Bbase = Wd1 + ((size_t)d * FC1_KB * FC1_OUT) * 32
                          + ((size_t)o0 + lane32) * 32 + half16;

    auto stage = [&](int s, int buf) {
        int kbg0 = s * 4;
        for (int i = wv; i < 32; i += 4) {
            int kb = (i >> 2) & 3, sub = i & 3;
            int kbg = kbg0 + kb;
            if (i < 16) {
                GLOAD16(Abase + (size_t)kbg * (TB * 32) + sub * 1024,
                        stg + buf * 32768 + i * 1024);
            } else {
                GLOAD16(Bbase + (size_t)kbg * (FC1_OUT * 32) + sub * 1024,
                        stg + buf * 32768 + i * 1024);
            }
        }
    };

    stage(0, 0);
    __syncthreads();

#pragma unroll 1
    for (int q = 0; q < 49; ++q) {
        int buf = q & 1;
        if (q + 1 < 49) stage(q + 1, buf ^ 1);
        const u8* A_ = stg + buf * 32768;
        const u8* B_ = A_ + 16384;
#pragma unroll
        for (int kb = 0; kb < 4; ++kb) {
            v4i A0 = *(const v4i*)(A_ + (kb * 4 + wm * 2 + 0) * 1024 + lane * 16);
            v4i A1 = *(const v4i*)(A_ + (kb * 4 + wm * 2 + 1) * 1024 + lane * 16);
            v4i B0 = *(const v4i*)(B_ + (kb * 4 + wn * 2 + 0) * 1024 + lane * 16);
            v4i B1 = *(const v4i*)(B_ + (kb * 4 + wn * 2 + 1) * 1024 + lane * 16);
            acc00 = __builtin_amdgcn_mfma_i32_32x32x32_i8(A0, B0, acc00, 0, 0, 0);
            acc01 = __builtin_amdgcn_mfma_i32_32x32x32_i8(A0, B1, acc01, 0, 0, 0);
            acc10 = __builtin_amdgcn_mfma_i32_32x32x32_i8(A1, B0, acc10, 0, 0, 0);
            acc11 = __builtin_amdgcn_mfma_i32_32x32x32_i8(A1, B1, acc11, 0, 0, 0);
        }
        __syncthreads();
    }

    int rhi = (lane >> 5) << 2;
    int* Hd = Hpart + (size_t)d * TB * FC1_OUT;
#pragma unroll
    for (int r = 0; r < 16; ++r) {
        int row = (r & 3) + 8 * (r >> 2) + rhi;
        size_t b0 = (size_t)(tb0 + wm * 64 + row) * FC1_OUT + o0 + wn * 64 + lane32;
        Hd[b0]                      = acc00[r];
        Hd[b0 + 32]                 = acc01[r];
        Hd[b0 + (size_t)32 * FC1_OUT]      = acc10[r];
        Hd[b0 + (size_t)32 * FC1_OUT + 32] = acc11[r];
    }
}

// ---------------------------------------------------------------------------
// K5: combine digit partials (exact i64) + IF over T -> s3[tb][2048] u8
// ---------------------------------------------------------------------------
__global__ __launch_bounds__(256) void k5_if3(
    const int* __restrict__ Hpart, u8* __restrict__ s3)
{
    int g = blockIdx.x * 256 + threadIdx.x;   // 128*2048
    int b = g >> 11;
    int o = g & 2047;
    double v = 0.0;
#pragma unroll
    for (int t = 0; t < 8; ++t) {
        size_t idx = (size_t)(t * BATCH + b) * FC1_OUT + o;
        long c = 0;
#pragma unroll
        for (int d = 0; d < FC1_DIGITS; ++d)
            c += ((long)Hpart[(size_t)d * TB * FC1_OUT + idx]) << (8 * d);
        double h = v + (double)c * FC1_INVSCALE;
        int s = (h >= 1.0);
        v = s ? 0.0 : h;
        s3[idx] = (u8)s;
    }
}

// ---------------------------------------------------------------------------
// K6: fc2  h4[tb][16(10 used)] = sum_i s3[tb][i]*fw2[o][i], f64, wave-reduced
// ---------------------------------------------------------------------------
__global__ __launch_bounds__(64) void k6_fc2(
    const u8* __restrict__ s3, const float* __restrict__ fw2,
    double* __restrict__ h4)
{
    int tb = blockIdx.x;
    int lane = threadIdx.x;
    double acc[10];
#pragma unroll
    for (int o = 0; o < 10; ++o) acc[o] = 0.0;

    for (int k = 0; k < 32; ++k) {
        int i = k * 64 + lane;
        double zd = (double)s3[(size_t)tb * FC1_OUT + i];
#pragma unroll
        for (int o = 0; o < 10; ++o)
            acc[o] += zd * (double)fw2[o * FC1_OUT + i];
    }
#pragma unroll
    for (int o = 0; o < 10; ++o) {
#pragma unroll
        for (int off = 32; off >= 1; off >>= 1)
            acc[o] += __shfl_down(acc[o], off);
    }
    if (lane == 0) {
#pragma unroll
        for (int o = 0; o < 10; ++o) h4[(size_t)tb * 16 + o] = acc[o];
    }
}

// ---------------------------------------------------------------------------
// K7: IF over T on h4 + mean -> out[b][10] f32
// ---------------------------------------------------------------------------
__global__ __launch_bounds__(256) void k7_if4_mean(
    const double* __restrict__ h4, float* __restrict__ out)
{
    int g = blockIdx.x * 256 + threadIdx.x;
    if (g >= BATCH * FC2_OUT) return;
    int b = g / 10;
    int o = g - b * 10;
    double v = 0.0; int cnt = 0;
#pragma unroll
    for (int t = 0; t < 8; ++t) {
        double h = v + h4[(size_t)(t * BATCH + b) * 16 + o];
        int s = (h >= 1.0);
        cnt += s;
        v = s ? 0.0 : h;
    }
    out[b * 10 + o] = (float)cnt * 0.125f;
}

// ---------------------------------------------------------------------------
extern "C" void kernel_launch(void* const* d_in, const int* in_sizes, int n_in,
                              void* d_out, int out_size, void* d_ws, size_t ws_size,
                              hipStream_t stream)
{
    const float* x   = (const float*)d_in[0];
    const float* w1  = (const float*)d_in[1];
    const float* g1  = (const float*)d_in[2];
    const float* b1  = (const float*)d_in[3];
    const float* m1  = (const float*)d_in[4];
    const float* v1  = (const float*)d_in[5];
    const float* w2  = (const float*)d_in[6];
    const float* g2  = (const float*)d_in[7];
    const float* b2  = (const float*)d_in[8];
    const float* m2  = (const float*)d_in[9];
    const float* v2  = (const float*)d_in[10];
    const float* fw1 = (const float*)d_in[11];
    const float* fw2 = (const float*)d_in[12];
    float* out = (float*)d_out;

    char* ws = (char*)d_ws;
    size_t off = 0;
    auto alloc = [&](size_t sz) { size_t o = off; off = (off + sz + 255) & ~(size_t)255; return o; };

    size_t o_p1 = alloc((size_t)TSTEPS * BATCH * CH * 8 * 4);   // 4 MB
    size_t o_z  = alloc((size_t)TB * FC1_IN);                   // 6.4 MB (z2)
    size_t o_s3 = alloc((size_t)TB * FC1_OUT);                  // 2.1 MB
    size_t o_h4 = alloc((size_t)TB * 16 * 8);                   // 128 KB
    size_t o_wd = alloc((size_t)W2_DIGITS * 9 * CH * CH);       // 590 KB (Bt)
    size_t o_h2 = off;
    // shared region: h2T (205.5 MB f64) lives k2->k3; after k3, Wd1 (64.2 MB)
    // and Hpart (41.9 MB) alias the same region (106 MB total).
    size_t h2_f64_bytes = (size_t)TB * CH * NPIX2 * 8;
    int is64 = (off + h2_f64_bytes <= ws_size) ? 1 : 0;
    size_t wd1_bytes = (size_t)FC1_DIGITS * FC1_KB * FC1_OUT * 32;  // 64,225,280

    u32*    p1bits = (u32*)(ws + o_p1);
    u8*     z2     = (u8*)(ws + o_z);
    u8*     s3     = (u8*)(ws + o_s3);
    double* h4     = (double*)(ws + o_h4);
    s8*     Bt     = (s8*)(ws + o_wd);
    void*   h2T    = (void*)(ws + o_h2);
    s8*     Wd1    = (s8*)(ws + o_h2);                 // alias, disjoint lifetime
    int*    Hpart  = (int*)(ws + o_h2 + wd1_bytes);    // alias, after Wd1

    k2w_quant<<<dim3((CH * CH + 255) / 256), dim3(256), 0, stream>>>(w2, Bt);

    k1_conv1_if_pool<<<dim3(BATCH * CH), dim3(256), 0, stream>>>(
        x, w1, g1, b1, m1, v1, p1bits);

    k2_conv2_i8<<<dim3(TB), dim3(1024), 0, stream>>>(
        p1bits, Bt, g2, b2, m2, v2, h2T, is64);

    k3_if2_pool<<<dim3(BATCH * 49 * CH / 256), dim3(256), 0, stream>>>(
        h2T, z2, is64);

    k4w_quant<<<dim3((FC1_KB * FC1_OUT + 255) / 256), dim3(256), 0, stream>>>(
        fw1, Wd1);

    k4_fc1_i8<<<dim3(640), dim3(256), 0, stream>>>(z2, Wd1, Hpart);

    k5_if3<<<dim3(BATCH * FC1_OUT / 256), dim3(256), 0, stream>>>(Hpart, s3);

    k6_fc2<<<dim3(TB), dim3(64), 0, stream>>>(s3, fw2, h4);

    k7_if4_mean<<<dim3((BATCH * FC2_OUT + 255) / 256), dim3(256), 0, stream>>>(h4, out);
}

// Round 6
// 412.482 us; speedup vs baseline: 6.1234x; 1.0388x over previous
//
#include <hip/hip_runtime.h>
#include <stdint.h>

typedef unsigned int u32;
typedef unsigned long long u64;
typedef unsigned char u8;
typedef signed char s8;
typedef int v4i __attribute__((ext_vector_type(4)));
typedef int v16i __attribute__((ext_vector_type(16)));

#define TSTEPS 8
#define BATCH 128
#define CH 128
#define NPIX1 784   // 28*28
#define NPIX2 196   // 14*14
#define TB 1024     // TSTEPS*BATCH
#define FC1_OUT 2048
#define FC1_IN 6272 // 128*49
#define FC2_OUT 10

// conv2: 4 signed base-256 digits, scale 2^32
#define W2_DIGITS 4
#define W2_SCALE 4294967296.0               // 2^32
#define W2_INVSCALE 2.3283064365386963e-10  // 2^-32

// fc1: 5 signed base-256 digits, scale 2^39
#define FC1_DIGITS 5
#define FC1_KB 196                          // 6272/32
#define FC1_SCALE 549755813888.0            // 2^39
#define FC1_INVSCALE 1.8189894035458565e-12 // 2^-39

typedef __attribute__((address_space(3))) u32 lds_u32;
typedef const __attribute__((address_space(1))) u32 glb_u32;
#define GLOAD16(G, L) __builtin_amdgcn_global_load_lds((glb_u32*)(G), (lds_u32*)(L), 16, 0, 0)

// ---------------------------------------------------------------------------
// K1: conv1(1->128,3x3,SAME) + bn1 + IF over T=8 (constant input) + 2x2 maxpool
// output: p1bits[t][b][ci][8 u32]  (bit p = pooled spike at 14x14 pixel p)
// ---------------------------------------------------------------------------
__global__ __launch_bounds__(256) void k1_conv1_if_pool(
    const float* __restrict__ x, const float* __restrict__ w1,
    const float* __restrict__ g1, const float* __restrict__ b1,
    const float* __restrict__ m1, const float* __restrict__ v1,
    u32* __restrict__ p1bits)
{
    int blk = blockIdx.x;
    int b  = blk >> 7;
    int co = blk & 127;
    int tid = threadIdx.x;

    __shared__ u32 sbyte[NPIX1];

    double wk[9];
#pragma unroll
    for (int k = 0; k < 9; ++k) wk[k] = (double)w1[co * 9 + k];
    double inv  = (double)g1[co] / sqrt((double)v1[co] + 1e-5);
    double beta = (double)b1[co] - (double)m1[co] * inv;

    const float* xb = x + (size_t)b * NPIX1;

    for (int p = tid; p < NPIX1; p += 256) {
        int y  = p / 28;
        int xx = p - y * 28;
        double acc = 0.0;
#pragma unroll
        for (int dy = 0; dy < 3; ++dy) {
            int iy = y + dy - 1;
#pragma unroll
            for (int dx = 0; dx < 3; ++dx) {
                int ix = xx + dx - 1;
                if (iy >= 0 && iy < 28 && ix >= 0 && ix < 28)
                    acc += (double)xb[iy * 28 + ix] * wk[dy * 3 + dx];
            }
        }
        double yv = acc * inv + beta;
        double v = 0.0; u32 byte = 0;
#pragma unroll
        for (int t = 0; t < 8; ++t) {
            double h = v + yv;
            int s = (h >= 1.0);
            byte |= (u32)s << t;
            v = s ? 0.0 : h;
        }
        sbyte[p] = byte;
    }
    __syncthreads();

    u32 pooled = 0;
    if (tid < NPIX2) {
        int y14 = tid / 14;
        int x14 = tid - y14 * 14;
        int p0 = (2 * y14) * 28 + 2 * x14;
        pooled = sbyte[p0] | sbyte[p0 + 1] | sbyte[p0 + 28] | sbyte[p0 + 29];
    }

    int lane = tid & 63;
    int wv   = tid >> 6;
    u32 val = 0;
#pragma unroll
    for (int t = 0; t < 8; ++t) {
        u64 m = __ballot((pooled >> t) & 1);
        u32 piece = (lane & 1) ? (u32)(m >> 32) : (u32)m;
        if ((lane >> 1) == t) val = piece;
    }
    if (lane < 16) {
        int t = lane >> 1, half = lane & 1;
        p1bits[((size_t)(t * BATCH + b) * CH + co) * 8 + wv * 2 + half] = val;
    }
}

// ---------------------------------------------------------------------------
// K2w: quantize conv2 weights to 4 signed base-256 digits at scale 2^32.
// Fragment-order layout: Bt[(((d*9+tap)*4+ks)*4+Nt)*1024 + l*16 + bp]
// ---------------------------------------------------------------------------
__global__ __launch_bounds__(256) void k2w_quant(
    const float* __restrict__ w2, s8* __restrict__ Bt)
{
    int g = blockIdx.x * 256 + threadIdx.x;   // co*128+ci
    if (g >= CH * CH) return;
    int co = g >> 7, ci = g & 127;
    int ks = ci >> 5, rem = ci & 31, half = rem >> 4, bp = rem & 15;
    int l = (co & 31) | (half << 5);
    int Nt = co >> 5;
#pragma unroll
    for (int k = 0; k < 9; ++k) {
        double wd = (double)w2[(size_t)g * 9 + k] * W2_SCALE;
        long r = (long)llrint(wd);
#pragma unroll
        for (int d = 0; d < W2_DIGITS; ++d) {
            int dg = (int)(((r + 128) & 255) - 128);
            r = (r - (long)dg) >> 8;
            Bt[((size_t)(((d * 9 + k) * 4 + ks) * 4 + Nt)) * 1024 + l * 16 + bp] = (s8)dg;
        }
    }
}

// ---------------------------------------------------------------------------
// K2: FUSED conv2+bn2+IF2+pool. Block = (b, co-quarter), 448 thr = 7 waves
// (wave = 32-pixel M tile). Loops t=0..7 with IF state v[16] (f64) held in
// registers. Per t: stage spike plane (32KB LDS), 16 (digit,ks) phases with
// double-buffered 9KB B slabs (t-invariant stream), exact i64 carry, f64
// bn2+IF, spikes -> LDS, 2x2 pool, write z2[kb][tb][32] bytes directly.
// No h2 intermediate. 57KB LDS, <=128 VGPR -> 2 blocks/CU.
// ---------------------------------------------------------------------------
__global__ __launch_bounds__(448, 4) void k2_conv2_if_pool(
    const u32* __restrict__ p1bits, const s8* __restrict__ Bt,
    const float* __restrict__ g2, const float* __restrict__ bb2,
    const float* __restrict__ m2, const float* __restrict__ v2,
    u8* __restrict__ z2)
{
    int bx = blockIdx.x;          // 512 = 128 b x 4 cq
    int b  = bx >> 2;
    int cq = bx & 3;              // co tile (Nt)

    int tid = threadIdx.x;
    int lane = tid & 63;
    int lane32 = lane & 31;
    int khalf = (lane >> 5) << 4;
    int mt = __builtin_amdgcn_readfirstlane(tid >> 6);  // 0..6

    __shared__ u8 sp[32768];          // spikes [256 halo rows][128 ci], swizzled
    __shared__ u8 bbuf[2 * 9216];     // B slab dbuf: 9 taps x 1024 B
    __shared__ u8 sbuf[NPIX2 * 32];   // spike bytes [pix][co32] for pooling

    // zero spike halo once (borders stay 0 forever)
    uint4* sp16 = (uint4*)sp;
    for (int i = tid; i < 2048; i += 448) sp16[i] = make_uint4(0u, 0u, 0u, 0u);

    // per-lane bn2 constants (co = cq*32 + lane32)
    int co = cq * 32 + lane32;
    double binv  = (double)g2[co] / sqrt((double)v2[co] + 1e-5);
    double bbeta = (double)bb2[co] - (double)m2[co] * binv;

    // A-fragment geometry
    int p  = mt * 32 + lane32;
    int pe = (p < NPIX2) ? p : (NPIX2 - 1);
    int py = (pe * 2341) >> 15;
    int px = pe - py * 14;
    int rb = py * 16 + px;
    int rhi = (lane >> 5) * 4;

    // stage B slab for global phase 0 (d=0, ks=0)
    for (int i = mt; i < 9; i += 7) {
        const s8* src = Bt + ((size_t)((i * 4 + 0) * 4 + cq)) * 1024 + lane * 16;
        GLOAD16(src, bbuf + i * 1024);
    }

    double vstate[16];
#pragma unroll
    for (int r = 0; r < 16; ++r) vstate[r] = 0.0;

#pragma unroll 1
    for (int t = 0; t < TSTEPS; ++t) {
        int tb = t * BATCH + b;
        // stage spike plane for t (bit -> i8), interior fully rewritten
        for (int c = tid; c < NPIX2 * 8; c += 448) {
            int pp = c >> 3, cg = c & 7;
            int ci0 = cg * 16;
            int ppy = (pp * 2341) >> 15;
            int ppx = pp - ppy * 14;
            int row = (ppy + 1) * 16 + (ppx + 1);
            int wi = pp >> 5, bit = pp & 31;
            const u32* bp = p1bits + ((size_t)tb * CH + ci0) * 8 + wi;
            u32 wd0 = 0, wd1 = 0, wd2 = 0, wd3 = 0;
#pragma unroll
            for (int j = 0; j < 4; ++j) {
                wd0 |= ((bp[(j     ) * 8] >> bit) & 1u) << (j * 8);
                wd1 |= ((bp[(j +  4) * 8] >> bit) & 1u) << (j * 8);
                wd2 |= ((bp[(j +  8) * 8] >> bit) & 1u) << (j * 8);
                wd3 |= ((bp[(j + 12) * 8] >> bit) & 1u) << (j * 8);
            }
            int addr = (row * 128 + ci0) ^ ((row & 7) << 4);
            *(uint4*)(sp + addr) = make_uint4(wd0, wd1, wd2, wd3);
        }
        __syncthreads();

        long carry[16];
#pragma unroll
        for (int r = 0; r < 16; ++r) carry[r] = 0;
        v16i a0;
#pragma unroll
        for (int r = 0; r < 16; ++r) a0[r] = 0;

#pragma unroll 1
        for (int ph = 0; ph < 16; ++ph) {
            int gp = t * 16 + ph;
            int buf = gp & 1;
            // prefetch next phase's B slab (periodic mod 16, t-invariant)
            if (gp + 1 < TSTEPS * 16) {
                int np = (gp + 1) & 15;
                int d1 = np >> 2, ks1 = np & 3;
                for (int i = mt; i < 9; i += 7) {
                    const s8* src = Bt + ((size_t)(((d1 * 9 + i) * 4 + ks1) * 4 + cq)) * 1024 + lane * 16;
                    GLOAD16(src, bbuf + (buf ^ 1) * 9216 + i * 1024);
                }
            }
            // compute current phase: 9 taps, 1 Nt
            {
                int ks = ph & 3;
                const u8* bbp = bbuf + buf * 9216;
#pragma unroll
                for (int tap = 0; tap < 9; ++tap) {
                    int dy = tap / 3, dx = tap - (tap / 3) * 3;
                    int rowidx = rb + dy * 16 + dx;
                    int swz = (rowidx & 7) << 4;
                    v4i A  = *(const v4i*)(sp + ((rowidx * 128 + ks * 32 + khalf) ^ swz));
                    v4i B0 = *(const v4i*)(bbp + tap * 1024 + lane * 16);
                    a0 = __builtin_amdgcn_mfma_i32_32x32x32_i8(A, B0, a0, 0, 0, 0);
                }
            }
            if ((ph & 3) == 3) {  // end of digit
                int sh = 8 * (ph >> 2);
#pragma unroll
                for (int r = 0; r < 16; ++r) {
                    carry[r] += ((long)a0[r]) << sh;
                    a0[r] = 0;
                }
            }
            __syncthreads();
        }

        // epilogue for t: bn2 + IF step, spike byte -> sbuf
#pragma unroll
        for (int r = 0; r < 16; ++r) {
            int pix = mt * 32 + (r & 3) + 8 * (r >> 2) + rhi;
            double hin = (double)carry[r] * W2_INVSCALE * binv + bbeta;
            double hv = vstate[r] + hin;
            int s = (hv >= 1.0);
            vstate[r] = s ? 0.0 : hv;
            if (pix < NPIX2) sbuf[pix * 32 + lane32] = (u8)s;
        }
        __syncthreads();

        // 2x2 pool -> z2 bytes
        for (int j = tid; j < 49 * 32; j += 448) {
            int w49 = j >> 5, c32 = j & 31;
            int wy = w49 / 7, wx = w49 - wy * 7;
            int p0 = (2 * wy) * 14 + 2 * wx;
            u8 s = sbuf[p0 * 32 + c32] | sbuf[(p0 + 1) * 32 + c32]
                 | sbuf[(p0 + 14) * 32 + c32] | sbuf[(p0 + 15) * 32 + c32];
            int i = (cq * 32 + c32) * 49 + w49;
            z2[((size_t)(i >> 5) * TB + tb) * 32 + (i & 31)] = s;
        }
        __syncthreads();
    }
}

// ---------------------------------------------------------------------------
// K4w: quantize fc1 weights to 5 signed base-256 digits at scale 2^39.
// Layout Wd1[d][kb][o][32] i8.
// ---------------------------------------------------------------------------
__global__ __launch_bounds__(256) void k4w_quant(
    const float* __restrict__ fw, s8* __restrict__ Wd1)
{
    int g = blockIdx.x * 256 + threadIdx.x;   // kb*2048 + o
    if (g >= FC1_KB * FC1_OUT) return;
    int o = g & 2047, kb = g >> 11;

    u32 tmp[FC1_DIGITS][8];
#pragma unroll
    for (int d = 0; d < FC1_DIGITS; ++d)
#pragma unroll
        for (int q = 0; q < 8; ++q) tmp[d][q] = 0;

#pragma unroll
    for (int j = 0; j < 32; ++j) {
        double wd = (double)fw[(size_t)o * FC1_IN + kb * 32 + j] * FC1_SCALE;
        long r = (long)llrint(wd);
#pragma unroll
        for (int d = 0; d < FC1_DIGITS; ++d) {
            int dg = (int)(((r + 128) & 255) - 128);
            r = (r - (long)dg) >> 8;
            tmp[d][j >> 2] |= (u32)(dg & 255) << ((j & 3) * 8);
        }
    }
#pragma unroll
    for (int d = 0; d < FC1_DIGITS; ++d) {
        u32* dst = (u32*)(Wd1 + (((size_t)d * FC1_KB + kb) * FC1_OUT + o) * 32);
        *(uint4*)dst       = make_uint4(tmp[d][0], tmp[d][1], tmp[d][2], tmp[d][3]);
        *(uint4*)(dst + 4) = make_uint4(tmp[d][4], tmp[d][5], tmp[d][6], tmp[d][7]);
    }
}

// ---------------------------------------------------------------------------
// K4: fc1 via i8 MFMA, digit-split across blocks -> i32 partials.
// Grid 640 = 8 XCD x (2 nt x 5 d) x 8 mt. Block 256 thr = 4 waves (2wm x 2wn),
// tile 128tb x 128o, wave tile 64x64 (2x2 subtiles). 49 phases x 4 kb,
// 64 KB LDS double-buffer -> 2 blocks/CU.
// ---------------------------------------------------------------------------
__global__ __launch_bounds__(256, 2) void k4_fc1_i8(
    const u8* __restrict__ z2, const s8* __restrict__ Wd1,
    int* __restrict__ Hpart)
{
    __shared__ u8 stg[2 * 32768];   // [buf][A 16KB | B 16KB]

    int bx = blockIdx.x;
    int xcd = bx & 7, g = bx >> 3;        // g 0..79
    int ntd = xcd * 10 + (g >> 3);        // 0..79
    int mt = g & 7;
    int nt = ntd / 5, d = ntd - nt * 5;

    int tid = threadIdx.x;
    int lane = tid & 63, lane32 = lane & 31;
    int half16 = (lane >> 5) << 4;
    int wv = __builtin_amdgcn_readfirstlane(tid >> 6);
    int wm = wv >> 1, wn = wv & 1;

    int tb0 = mt * 128, o0 = nt * 128;

    v16i acc00, acc01, acc10, acc11;
#pragma unroll
    for (int r = 0; r < 16; ++r) { acc00[r] = 0; acc01[r] = 0; acc10[r] = 0; acc11[r] = 0; }

    const u8* Abase = z2 + ((size_t)tb0 + lane32) * 32 + half16;
    const s8* Bbase = Wd1 + ((size_t)d * FC1_KB * FC1_OUT) * 32
                          + ((size_t)o0 + lane32) * 32 + half16;

    auto stage = [&](int s, int buf) {
        int kbg0 = s * 4;
        for (int i = wv; i < 32; i += 4) {
            int kb = (i >> 2) & 3, sub = i & 3;
            int kbg = kbg0 + kb;
            if (i < 16) {
                GLOAD16(Abase + (size_t)kbg * (TB * 32) + sub * 1024,
                        stg + buf * 32768 + i * 1024);
            } else {
                GLOAD16(Bbase + (size_t)kbg * (FC1_OUT * 32) + sub * 1024,
                        stg + buf * 32768 + i * 1024);
            }
        }
    };

    stage(0, 0);
    __syncthreads();

#pragma unroll 1
    for (int q = 0; q < 49; ++q) {
        int buf = q & 1;
        if (q + 1 < 49) stage(q + 1, buf ^ 1);
        const u8* A_ = stg + buf * 32768;
        const u8* B_ = A_ + 16384;
#pragma unroll
        for (int kb = 0; kb < 4; ++kb) {
            v4i A0 = *(const v4i*)(A_ + (kb * 4 + wm * 2 + 0) * 1024 + lane * 16);
            v4i A1 = *(const v4i*)(A_ + (kb * 4 + wm * 2 + 1) * 1024 + lane * 16);
            v4i B0 = *(const v4i*)(B_ + (kb * 4 + wn * 2 + 0) * 1024 + lane * 16);
            v4i B1 = *(const v4i*)(B_ + (kb * 4 + wn * 2 + 1) * 1024 + lane * 16);
            acc00 = __builtin_amdgcn_mfma_i32_32x32x32_i8(A0, B0, acc00, 0, 0, 0);
            acc01 = __builtin_amdgcn_mfma_i32_32x32x32_i8(A0, B1, acc01, 0, 0, 0);
            acc10 = __builtin_amdgcn_mfma_i32_32x32x32_i8(A1, B0, acc10, 0, 0, 0);
            acc11 = __builtin_amdgcn_mfma_i32_32x32x32_i8(A1, B1, acc11, 0, 0, 0);
        }
        __syncthreads();
    }

    int rhi = (lane >> 5) << 2;
    int* Hd = Hpart + (size_t)d * TB * FC1_OUT;
#pragma unroll
    for (int r = 0; r < 16; ++r) {
        int row = (r & 3) + 8 * (r >> 2) + rhi;
        size_t b0 = (size_t)(tb0 + wm * 64 + row) * FC1_OUT + o0 + wn * 64 + lane32;
        Hd[b0]                      = acc00[r];
        Hd[b0 + 32]                 = acc01[r];
        Hd[b0 + (size_t)32 * FC1_OUT]      = acc10[r];
        Hd[b0 + (size_t)32 * FC1_OUT + 32] = acc11[r];
    }
}

// ---------------------------------------------------------------------------
// K5: combine digit partials (exact i64) + IF over T -> s3[tb][2048] u8
// ---------------------------------------------------------------------------
__global__ __launch_bounds__(256) void k5_if3(
    const int* __restrict__ Hpart, u8* __restrict__ s3)
{
    int g = blockIdx.x * 256 + threadIdx.x;   // 128*2048
    int b = g >> 11;
    int o = g & 2047;
    double v = 0.0;
#pragma unroll
    for (int t = 0; t < 8; ++t) {
        size_t idx = (size_t)(t * BATCH + b) * FC1_OUT + o;
        long c = 0;
#pragma unroll
        for (int d = 0; d < FC1_DIGITS; ++d)
            c += ((long)Hpart[(size_t)d * TB * FC1_OUT + idx]) << (8 * d);
        double h = v + (double)c * FC1_INVSCALE;
        int s = (h >= 1.0);
        v = s ? 0.0 : h;
        s3[idx] = (u8)s;
    }
}

// ---------------------------------------------------------------------------
// K6: fc2  h4[tb][16(10 used)] = sum_i s3[tb][i]*fw2[o][i], f64, wave-reduced
// ---------------------------------------------------------------------------
__global__ __launch_bounds__(64) void k6_fc2(
    const u8* __restrict__ s3, const float* __restrict__ fw2,
    double* __restrict__ h4)
{
    int tb = blockIdx.x;
    int lane = threadIdx.x;
    double acc[10];
#pragma unroll
    for (int o = 0; o < 10; ++o) acc[o] = 0.0;

    for (int k = 0; k < 32; ++k) {
        int i = k * 64 + lane;
        double zd = (double)s3[(size_t)tb * FC1_OUT + i];
#pragma unroll
        for (int o = 0; o < 10; ++o)
            acc[o] += zd * (double)fw2[o * FC1_OUT + i];
    }
#pragma unroll
    for (int o = 0; o < 10; ++o) {
#pragma unroll
        for (int off = 32; off >= 1; off >>= 1)
            acc[o] += __shfl_down(acc[o], off);
    }
    if (lane == 0) {
#pragma unroll
        for (int o = 0; o < 10; ++o) h4[(size_t)tb * 16 + o] = acc[o];
    }
}

// ---------------------------------------------------------------------------
// K7: IF over T on h4 + mean -> out[b][10] f32
// ---------------------------------------------------------------------------
__global__ __launch_bounds__(256) void k7_if4_mean(
    const double* __restrict__ h4, float* __restrict__ out)
{
    int g = blockIdx.x * 256 + threadIdx.x;
    if (g >= BATCH * FC2_OUT) return;
    int b = g / 10;
    int o = g - b * 10;
    double v = 0.0; int cnt = 0;
#pragma unroll
    for (int t = 0; t < 8; ++t) {
        double h = v + h4[(size_t)(t * BATCH + b) * 16 + o];
        int s = (h >= 1.0);
        cnt += s;
        v = s ? 0.0 : h;
    }
    out[b * 10 + o] = (float)cnt * 0.125f;
}

// ---------------------------------------------------------------------------
extern "C" void kernel_launch(void* const* d_in, const int* in_sizes, int n_in,
                              void* d_out, int out_size, void* d_ws, size_t ws_size,
                              hipStream_t stream)
{
    const float* x   = (const float*)d_in[0];
    const float* w1  = (const float*)d_in[1];
    const float* g1  = (const float*)d_in[2];
    const float* b1  = (const float*)d_in[3];
    const float* m1  = (const float*)d_in[4];
    const float* v1  = (const float*)d_in[5];
    const float* w2  = (const float*)d_in[6];
    const float* g2  = (const float*)d_in[7];
    const float* b2  = (const float*)d_in[8];
    const float* m2  = (const float*)d_in[9];
    const float* v2  = (const float*)d_in[10];
    const float* fw1 = (const float*)d_in[11];
    const float* fw2 = (const float*)d_in[12];
    float* out = (float*)d_out;

    char* ws = (char*)d_ws;
    size_t off = 0;
    auto alloc = [&](size_t sz) { size_t o = off; off = (off + sz + 255) & ~(size_t)255; return o; };

    size_t o_p1 = alloc((size_t)TSTEPS * BATCH * CH * 8 * 4);            // 4 MB
    size_t o_z  = alloc((size_t)TB * FC1_IN);                            // 6.4 MB (z2)
    size_t o_s3 = alloc((size_t)TB * FC1_OUT);                           // 2.1 MB
    size_t o_h4 = alloc((size_t)TB * 16 * 8);                            // 128 KB
    size_t o_wd = alloc((size_t)W2_DIGITS * 9 * CH * CH);                // 590 KB (Bt)
    size_t o_w1 = alloc((size_t)FC1_DIGITS * FC1_KB * FC1_OUT * 32);     // 64.2 MB (Wd1)
    size_t o_hp = alloc((size_t)FC1_DIGITS * TB * FC1_OUT * 4);          // 41.9 MB (Hpart)
    (void)ws_size;

    u32*    p1bits = (u32*)(ws + o_p1);
    u8*     z2     = (u8*)(ws + o_z);
    u8*     s3     = (u8*)(ws + o_s3);
    double* h4     = (double*)(ws + o_h4);
    s8*     Bt     = (s8*)(ws + o_wd);
    s8*     Wd1    = (s8*)(ws + o_w1);
    int*    Hpart  = (int*)(ws + o_hp);

    k2w_quant<<<dim3((CH * CH + 255) / 256), dim3(256), 0, stream>>>(w2, Bt);

    k4w_quant<<<dim3((FC1_KB * FC1_OUT + 255) / 256), dim3(256), 0, stream>>>(
        fw1, Wd1);

    k1_conv1_if_pool<<<dim3(BATCH * CH), dim3(256), 0, stream>>>(
        x, w1, g1, b1, m1, v1, p1bits);

    k2_conv2_if_pool<<<dim3(512), dim3(448), 0, stream>>>(
        p1bits, Bt, g2, b2, m2, v2, z2);

    k4_fc1_i8<<<dim3(640), dim3(256), 0, stream>>>(z2, Wd1, Hpart);

    k5_if3<<<dim3(BATCH * FC1_OUT / 256), dim3(256), 0, stream>>>(Hpart, s3);

    k6_fc2<<<dim3(TB), dim3(64), 0, stream>>>(s3, fw2, h4);

    k7_if4_mean<<<dim3((BATCH * FC2_OUT + 255) / 256), dim3(256), 0, stream>>>(h4, out);
}

// Round 8
// 408.970 us; speedup vs baseline: 6.1760x; 1.0086x over previous
//
#include <hip/hip_runtime.h>
#include <stdint.h>

typedef unsigned int u32;
typedef unsigned long long u64;
typedef unsigned char u8;
typedef signed char s8;
typedef int v4i __attribute__((ext_vector_type(4)));
typedef int v16i __attribute__((ext_vector_type(16)));

#define TSTEPS 8
#define BATCH 128
#define CH 128
#define NPIX1 784   // 28*28
#define NPIX2 196   // 14*14
#define TB 1024     // TSTEPS*BATCH
#define FC1_OUT 2048
#define FC1_IN 6272 // 128*49
#define FC2_OUT 10

// conv2: 4 signed base-256 digits, scale 2^32
#define W2_DIGITS 4
#define W2_SCALE 4294967296.0               // 2^32
#define W2_INVSCALE 2.3283064365386963e-10  // 2^-32

// fc1: 4 signed base-256 digits, scale 2^33 (|fw1|max~0.11 -> |r|<2^31)
#define FC1_DIGITS 4
#define FC1_KB 196                          // 6272/32
#define FC1_SCALE 8589934592.0              // 2^33
#define FC1_INVSCALE 1.1641532182693481e-10 // 2^-33

#define P1S_PITCH 25216                     // 197 rows x 128 (row 196 = zeros)

typedef __attribute__((address_space(3))) u32 lds_u32;
typedef const __attribute__((address_space(1))) u32 glb_u32;
#define GLOAD16(G, L) __builtin_amdgcn_global_load_lds((glb_u32*)(G), (lds_u32*)(L), 16, 0, 0)

// ---------------------------------------------------------------------------
// K1: conv1+bn1+IF(T=8, const input)+2x2 maxpool -> spike BYTES in k2's
// swizzled layout: p1s[tb][(pix*128+ci) ^ ((pix&7)<<4)] = 0/1.
// Block = (b, cg of 32 ci). 256 thr.
// ---------------------------------------------------------------------------
__global__ __launch_bounds__(256) void k1_conv1_if_pool(
    const float* __restrict__ x, const float* __restrict__ w1,
    const float* __restrict__ g1, const float* __restrict__ b1,
    const float* __restrict__ m1, const float* __restrict__ v1,
    u8* __restrict__ p1s)
{
    int bx = blockIdx.x;          // 512 = b*4 + cg
    int b = bx >> 2, cg = bx & 3;
    int tid = threadIdx.x;

    __shared__ float xs[NPIX1];
    __shared__ double wt[32][13];       // 9 w + inv + beta (pad 13 vs bank conflicts)
    __shared__ u8 sbits[NPIX1 * 32];    // 8-t-bit mask per (pix, co32)

    for (int i = tid; i < NPIX1; i += 256) xs[i] = x[(size_t)b * NPIX1 + i];
    if (tid < 32) {
        int co = cg * 32 + tid;
#pragma unroll
        for (int k = 0; k < 9; ++k) wt[tid][k] = (double)w1[co * 9 + k];
        double inv = (double)g1[co] / sqrt((double)v1[co] + 1e-5);
        wt[tid][9]  = inv;
        wt[tid][10] = (double)b1[co] - (double)m1[co] * inv;
    }
    __syncthreads();

    for (int i = tid; i < NPIX1 * 32; i += 256) {
        int co = i & 31, p = i >> 5;
        int y = p / 28, xx = p - y * 28;
        double acc = 0.0;
#pragma unroll
        for (int dy = 0; dy < 3; ++dy) {
            int iy = y + dy - 1;
#pragma unroll
            for (int dx = 0; dx < 3; ++dx) {
                int ix = xx + dx - 1;
                if (iy >= 0 && iy < 28 && ix >= 0 && ix < 28)
                    acc += (double)xs[iy * 28 + ix] * wt[co][dy * 3 + dx];
            }
        }
        double yv = acc * wt[co][9] + wt[co][10];
        double v = 0.0; u32 byte = 0;
#pragma unroll
        for (int t = 0; t < 8; ++t) {
            double h = v + yv;
            int s = (h >= 1.0);
            byte |= (u32)s << t;
            v = s ? 0.0 : h;
        }
        sbits[p * 32 + co] = (u8)byte;
    }
    __syncthreads();

    for (int i = tid; i < NPIX2 * 32; i += 256) {
        int co = i & 31, p14 = i >> 5;
        int y14 = p14 / 14, x14 = p14 - y14 * 14;
        int p0 = (2 * y14) * 28 + 2 * x14;
        u8 pv = sbits[p0 * 32 + co] | sbits[(p0 + 1) * 32 + co]
              | sbits[(p0 + 28) * 32 + co] | sbits[(p0 + 29) * 32 + co];
        int off = (p14 * 128 + cg * 32 + co) ^ ((p14 & 7) << 4);
#pragma unroll
        for (int t = 0; t < 8; ++t)
            p1s[(size_t)(t * BATCH + b) * P1S_PITCH + off] = (u8)((pv >> t) & 1);
    }
}

// ---------------------------------------------------------------------------
// K2w: quantize conv2 weights to 4 signed base-256 digits at scale 2^32.
// Fragment-order: Bt[(((d*9+tap)*4+ks)*4+Nt)*1024 + l*16 + bp]
// ---------------------------------------------------------------------------
__global__ __launch_bounds__(256) void k2w_quant(
    const float* __restrict__ w2, s8* __restrict__ Bt)
{
    int g = blockIdx.x * 256 + threadIdx.x;   // co*128+ci
    if (g >= CH * CH) return;
    int co = g >> 7, ci = g & 127;
    int ks = ci >> 5, rem = ci & 31, half = rem >> 4, bp = rem & 15;
    int l = (co & 31) | (half << 5);
    int Nt = co >> 5;
#pragma unroll
    for (int k = 0; k < 9; ++k) {
        double wd = (double)w2[(size_t)g * 9 + k] * W2_SCALE;
        long r = (long)llrint(wd);
#pragma unroll
        for (int d = 0; d < W2_DIGITS; ++d) {
            int dg = (int)(((r + 128) & 255) - 128);
            r = (r - (long)dg) >> 8;
            Bt[((size_t)(((d * 9 + k) * 4 + ks) * 4 + Nt)) * 1024 + l * 16 + bp] = (s8)dg;
        }
    }
}

// ---------------------------------------------------------------------------
// K2: FUSED conv2+bn2+IF2+pool. Block = (b, cq), 448 thr = 7 waves (Mtile).
// ks-major phases: per ks load 9 A-frags into regs ONCE, reuse over 4 digits
// (A LDS traffic /4). Spike plane staged per t via pure global_load_lds from
// k1's pre-swizzled p1s. B slabs (9KB) double-buffered, prefetch issued early.
// ---------------------------------------------------------------------------
__global__ __launch_bounds__(448, 3) void k2_conv2_if_pool(
    const u8* __restrict__ p1s, const s8* __restrict__ Bt,
    const float* __restrict__ g2, const float* __restrict__ bb2,
    const float* __restrict__ m2, const float* __restrict__ v2,
    u8* __restrict__ z2)
{
    int bx = blockIdx.x;          // 512 = b*4 + cq
    int b = bx >> 2, cq = bx & 3;

    int tid = threadIdx.x;
    int lane = tid & 63;
    int lane32 = lane & 31;
    int khalf = (lane >> 5) << 4;
    int mt = __builtin_amdgcn_readfirstlane(tid >> 6);  // 0..6
    int rhi = (lane >> 5) * 4;

    __shared__ u8 sp[P1S_PITCH];        // 197 rows x 128, swizzled
    __shared__ u8 bbuf[2 * 9216];       // B slab dbuf: 9 taps x 1024
    __shared__ u8 sbuf[NPIX2 * 32];     // spike bytes for pooling

    // zero the dummy row 196 (never rewritten)
    if (tid < 8) *(uint4*)(sp + 196 * 128 + tid * 16) = make_uint4(0u, 0u, 0u, 0u);

    // bn2 constants (co = cq*32 + lane32)
    int co = cq * 32 + lane32;
    double binv  = (double)g2[co] / sqrt((double)v2[co] + 1e-5);
    double bbeta = (double)bb2[co] - (double)m2[co] * binv;

    // per-lane tap neighbor pixel indices (196 = zero row)
    int p = mt * 32 + lane32;
    int valid = (p < NPIX2);
    int pe = valid ? p : 0;
    int py = pe / 14, px = pe - py * 14;
    int pixn[9];
#pragma unroll
    for (int tap = 0; tap < 9; ++tap) {
        int dy = tap / 3 - 1, dx = tap - (tap / 3) * 3 - 1;
        int ny = py + dy, nx = px + dx;
        int ok = valid & (ny >= 0) & (ny < 14) & (nx >= 0) & (nx < 14);
        pixn[tap] = ok ? (ny * 14 + nx) : 196;
    }

    // stage t=0 spike plane + (ks0,d0) B slab
    {
        const u8* src0 = p1s + (size_t)b * P1S_PITCH;
        for (int i = tid; i < 1568; i += 448) GLOAD16(src0 + i * 16, sp + i * 16);
        for (int u = mt; u < 9; u += 7)
            GLOAD16(Bt + ((size_t)(u * 16 + cq)) * 1024 + lane * 16, bbuf + u * 1024);
    }
    __syncthreads();

    double vst[16];
#pragma unroll
    for (int r = 0; r < 16; ++r) vst[r] = 0.0;

#pragma unroll 1
    for (int t = 0; t < TSTEPS; ++t) {
        long carry[16];
#pragma unroll
        for (int r = 0; r < 16; ++r) carry[r] = 0;

#pragma unroll 1
        for (int ks = 0; ks < 4; ++ks) {
            v4i A[9];
#pragma unroll 1
            for (int d = 0; d < 4; ++d) {
                int ph = ks * 4 + d;
                int buf = ph & 1;
                // prefetch next slab early (wraps mod 16; B stream t-periodic)
                {
                    int pn = (ph + 1) & 15;
                    int ksn = pn >> 2, dn = pn & 3;
                    for (int u = mt; u < 9; u += 7)
                        GLOAD16(Bt + ((size_t)(((dn * 9 + u) * 4 + ksn) * 4 + cq)) * 1024 + lane * 16,
                                bbuf + (buf ^ 1) * 9216 + u * 1024);
                }
                if (d == 0) {
#pragma unroll
                    for (int tap = 0; tap < 9; ++tap)
                        A[tap] = *(const v4i*)(sp + pixn[tap] * 128 +
                                 ((ks * 32 + khalf) ^ ((pixn[tap] & 7) << 4)));
                }
                v16i a;
#pragma unroll
                for (int r = 0; r < 16; ++r) a[r] = 0;
                const u8* bbp = bbuf + buf * 9216;
#pragma unroll
                for (int tap = 0; tap < 9; ++tap)
                    a = __builtin_amdgcn_mfma_i32_32x32x32_i8(
                        A[tap], *(const v4i*)(bbp + tap * 1024 + lane * 16), a, 0, 0, 0);
                int sh = 8 * d;
#pragma unroll
                for (int r = 0; r < 16; ++r) carry[r] += ((long)a[r]) << sh;
                __syncthreads();
            }
        }

        // issue next t's spike-plane staging early (sp reads all done)
        if (t + 1 < TSTEPS) {
            const u8* srcn = p1s + (size_t)((t + 1) * BATCH + b) * P1S_PITCH;
            for (int i = tid; i < 1568; i += 448) GLOAD16(srcn + i * 16, sp + i * 16);
        }

        // bn2 + IF step -> spike bytes
#pragma unroll
        for (int r = 0; r < 16; ++r) {
            int pix = mt * 32 + (r & 3) + 8 * (r >> 2) + rhi;
            double hin = (double)carry[r] * W2_INVSCALE * binv + bbeta;
            double hv = vst[r] + hin;
            int s = (hv >= 1.0);
            vst[r] = s ? 0.0 : hv;
            if (pix < NPIX2) sbuf[pix * 32 + lane32] = (u8)s;
        }
        __syncthreads();

        // 2x2 pool -> z2[kb][tb][32]
        int tb = t * BATCH + b;
        for (int j = tid; j < 49 * 32; j += 448) {
            int w49 = j >> 5, c32 = j & 31;
            int wy = w49 / 7, wx = w49 - wy * 7;
            int p0 = (2 * wy) * 14 + 2 * wx;
            u8 s = sbuf[p0 * 32 + c32] | sbuf[(p0 + 1) * 32 + c32]
                 | sbuf[(p0 + 14) * 32 + c32] | sbuf[(p0 + 15) * 32 + c32];
            int i2 = (cq * 32 + c32) * 49 + w49;
            z2[((size_t)(i2 >> 5) * TB + tb) * 32 + (i2 & 31)] = s;
        }
        __syncthreads();
    }
}

// ---------------------------------------------------------------------------
// K4w: quantize fc1 weights to 4 signed base-256 digits at scale 2^33.
// Layout Wd1[d][kb][o][32] i8.
// ---------------------------------------------------------------------------
__global__ __launch_bounds__(256) void k4w_quant(
    const float* __restrict__ fw, s8* __restrict__ Wd1)
{
    int g = blockIdx.x * 256 + threadIdx.x;   // kb*2048 + o
    if (g >= FC1_KB * FC1_OUT) return;
    int o = g & 2047, kb = g >> 11;

    u32 tmp[FC1_DIGITS][8];
#pragma unroll
    for (int d = 0; d < FC1_DIGITS; ++d)
#pragma unroll
        for (int q = 0; q < 8; ++q) tmp[d][q] = 0;

#pragma unroll
    for (int j = 0; j < 32; ++j) {
        double wd = (double)fw[(size_t)o * FC1_IN + kb * 32 + j] * FC1_SCALE;
        long r = (long)llrint(wd);
#pragma unroll
        for (int d = 0; d < FC1_DIGITS; ++d) {
            int dg = (int)(((r + 128) & 255) - 128);
            r = (r - (long)dg) >> 8;
            tmp[d][j >> 2] |= (u32)(dg & 255) << ((j & 3) * 8);
        }
    }
#pragma unroll
    for (int d = 0; d < FC1_DIGITS; ++d) {
        u32* dst = (u32*)(Wd1 + (((size_t)d * FC1_KB + kb) * FC1_OUT + o) * 32);
        *(uint4*)dst       = make_uint4(tmp[d][0], tmp[d][1], tmp[d][2], tmp[d][3]);
        *(uint4*)(dst + 4) = make_uint4(tmp[d][4], tmp[d][5], tmp[d][6], tmp[d][7]);
    }
}

// ---------------------------------------------------------------------------
// K4: fc1 via i8 MFMA, digit-split -> i32 partials. Grid 256 = mt8 x (nt8 x d4),
// bx = mt*32 + ntd so bx%8 = ntd%8 (same-B blocks colocate per XCD).
// Block 512 thr = 8 waves (2wm x 4wn), tile 128tb x 256o, wave 64x64 (2x2 sub).
// 98 phases x 2kb, 48KB LDS dbuf, prefetch issued early each phase.
// Staging source MUST be fragment-order: lane l <- row (base + l&31),
// byte-half (l>>5)*16, so linear LDS write (base + lane*16) = MFMA fragment.
// ---------------------------------------------------------------------------
__global__ __launch_bounds__(512, 2) void k4_fc1_i8(
    const u8* __restrict__ z2, const s8* __restrict__ Wd1,
    int* __restrict__ Hpart)
{
    __shared__ u8 stg[2 * 24576];   // [buf][A 8KB | B 16KB]

    int bx = blockIdx.x;
    int ntd = bx & 31, mt = bx >> 5;
    int nt = ntd >> 2, d = ntd & 3;

    int tid = threadIdx.x;
    int lane = tid & 63, lane32 = lane & 31;
    int half16 = (lane >> 5) << 4;
    int wv = __builtin_amdgcn_readfirstlane(tid >> 6);  // 0..7
    int wm = wv >> 2, wn = wv & 3;

    int tb0 = mt * 128, o0 = nt * 256;

    v16i acc00, acc01, acc10, acc11;
#pragma unroll
    for (int r = 0; r < 16; ++r) { acc00[r] = 0; acc01[r] = 0; acc10[r] = 0; acc11[r] = 0; }

    auto stage = [&](int q, int buf) {
        int kbg0 = q * 2;
        for (int i = wv; i < 24; i += 8) {
            if (i < 8) {
                int kbr = i >> 2, sub = i & 3;
                GLOAD16(z2 + ((size_t)(kbg0 + kbr) * TB + tb0 + sub * 32 + lane32) * 32 + half16,
                        stg + buf * 24576 + i * 1024);
            } else {
                int j = i - 8;
                int kbr = j >> 3, osub = j & 7;
                GLOAD16(Wd1 + (((size_t)d * FC1_KB + kbg0 + kbr) * FC1_OUT + o0 + osub * 32 + lane32) * 32 + half16,
                        stg + buf * 24576 + 8192 + j * 1024);
            }
        }
    };

    stage(0, 0);
    __syncthreads();

#pragma unroll 1
    for (int q = 0; q < 98; ++q) {
        int buf = q & 1;
        if (q + 1 < 98) stage(q + 1, buf ^ 1);
        const u8* A_ = stg + buf * 24576;
        const u8* B_ = A_ + 8192;
#pragma unroll
        for (int kbr = 0; kbr < 2; ++kbr) {
            v4i A0 = *(const v4i*)(A_ + (kbr * 4 + wm * 2 + 0) * 1024 + lane * 16);
            v4i A1 = *(const v4i*)(A_ + (kbr * 4 + wm * 2 + 1) * 1024 + lane * 16);
            v4i B0 = *(const v4i*)(B_ + (kbr * 8 + wn * 2 + 0) * 1024 + lane * 16);
            v4i B1 = *(const v4i*)(B_ + (kbr * 8 + wn * 2 + 1) * 1024 + lane * 16);
            acc00 = __builtin_amdgcn_mfma_i32_32x32x32_i8(A0, B0, acc00, 0, 0, 0);
            acc01 = __builtin_amdgcn_mfma_i32_32x32x32_i8(A0, B1, acc01, 0, 0, 0);
            acc10 = __builtin_amdgcn_mfma_i32_32x32x32_i8(A1, B0, acc10, 0, 0, 0);
            acc11 = __builtin_amdgcn_mfma_i32_32x32x32_i8(A1, B1, acc11, 0, 0, 0);
        }
        __syncthreads();
    }

    int rhi = (lane >> 5) << 2;
    int* Hd = Hpart + (size_t)d * TB * FC1_OUT;
#pragma unroll
    for (int r = 0; r < 16; ++r) {
        int row = (r & 3) + 8 * (r >> 2) + rhi;
        size_t b0 = (size_t)(tb0 + wm * 64 + row) * FC1_OUT + o0 + wn * 64 + lane32;
        Hd[b0]                             = acc00[r];
        Hd[b0 + 32]                        = acc01[r];
        Hd[b0 + (size_t)32 * FC1_OUT]      = acc10[r];
        Hd[b0 + (size_t)32 * FC1_OUT + 32] = acc11[r];
    }
}

// ---------------------------------------------------------------------------
// K5: combine digit partials (exact, c < 2^44) + IF over T -> s3
// ---------------------------------------------------------------------------
__global__ __launch_bounds__(256) void k5_if3(
    const int* __restrict__ Hpart, u8* __restrict__ s3)
{
    int g = blockIdx.x * 256 + threadIdx.x;   // 128*2048
    int b = g >> 11;
    int o = g & 2047;
    double v = 0.0;
#pragma unroll
    for (int t = 0; t < 8; ++t) {
        size_t idx = (size_t)(t * BATCH + b) * FC1_OUT + o;
        long c = 0;
#pragma unroll
        for (int d = 0; d < FC1_DIGITS; ++d)
            c += ((long)Hpart[(size_t)d * TB * FC1_OUT + idx]) << (8 * d);
        double h = v + (double)c * FC1_INVSCALE;
        int s = (h >= 1.0);
        v = s ? 0.0 : h;
        s3[idx] = (u8)s;
    }
}

// ---------------------------------------------------------------------------
// K6: fc2 h4[tb][16] = sum_i s3[tb][i]*fw2[o][i], f64. 256 thr, K-quarters.
// ---------------------------------------------------------------------------
__global__ __launch_bounds__(256) void k6_fc2(
    const u8* __restrict__ s3, const float* __restrict__ fw2,
    double* __restrict__ h4)
{
    int tb = blockIdx.x;
    int tid = threadIdx.x;
    int w = tid >> 6, lane = tid & 63;
    __shared__ double red[4][16];

    double acc[10];
#pragma unroll
    for (int o = 0; o < 10; ++o) acc[o] = 0.0;

#pragma unroll
    for (int it = 0; it < 8; ++it) {
        int i = w * 512 + it * 64 + lane;
        double zd = (double)s3[(size_t)tb * FC1_OUT + i];
#pragma unroll
        for (int o = 0; o < 10; ++o)
            acc[o] += zd * (double)fw2[o * FC1_OUT + i];
    }
#pragma unroll
    for (int o = 0; o < 10; ++o) {
#pragma unroll
        for (int off = 32; off >= 1; off >>= 1)
            acc[o] += __shfl_down(acc[o], off);
    }
    if (lane == 0) {
#pragma unroll
        for (int o = 0; o < 10; ++o) red[w][o] = acc[o];
    }
    __syncthreads();
    if (tid < 10)
        h4[(size_t)tb * 16 + tid] = red[0][tid] + red[1][tid] + red[2][tid] + red[3][tid];
}

// ---------------------------------------------------------------------------
// K7: IF over T on h4 + mean -> out[b][10] f32
// ---------------------------------------------------------------------------
__global__ __launch_bounds__(256) void k7_if4_mean(
    const double* __restrict__ h4, float* __restrict__ out)
{
    int g = blockIdx.x * 256 + threadIdx.x;
    if (g >= BATCH * FC2_OUT) return;
    int b = g / 10;
    int o = g - b * 10;
    double v = 0.0; int cnt = 0;
#pragma unroll
    for (int t = 0; t < 8; ++t) {
        double h = v + h4[(size_t)(t * BATCH + b) * 16 + o];
        int s = (h >= 1.0);
        cnt += s;
        v = s ? 0.0 : h;
    }
    out[b * 10 + o] = (float)cnt * 0.125f;
}

// ---------------------------------------------------------------------------
extern "C" void kernel_launch(void* const* d_in, const int* in_sizes, int n_in,
                              void* d_out, int out_size, void* d_ws, size_t ws_size,
                              hipStream_t stream)
{
    const float* x   = (const float*)d_in[0];
    const float* w1  = (const float*)d_in[1];
    const float* g1  = (const float*)d_in[2];
    const float* b1  = (const float*)d_in[3];
    const float* m1  = (const float*)d_in[4];
    const float* v1  = (const float*)d_in[5];
    const float* w2  = (const float*)d_in[6];
    const float* g2  = (const float*)d_in[7];
    const float* b2  = (const float*)d_in[8];
    const float* m2  = (const float*)d_in[9];
    const float* v2  = (const float*)d_in[10];
    const float* fw1 = (const float*)d_in[11];
    const float* fw2 = (const float*)d_in[12];
    float* out = (float*)d_out;

    char* ws = (char*)d_ws;
    size_t off = 0;
    auto alloc = [&](size_t sz) { size_t o = off; off = (off + sz + 255) & ~(size_t)255; return o; };

    size_t o_p1 = alloc((size_t)TB * P1S_PITCH);                         // 25.8 MB
    size_t o_z  = alloc((size_t)TB * FC1_IN);                            // 6.4 MB
    size_t o_s3 = alloc((size_t)TB * FC1_OUT);                           // 2.1 MB
    size_t o_h4 = alloc((size_t)TB * 16 * 8);                            // 128 KB
    size_t o_wd = alloc((size_t)W2_DIGITS * 9 * CH * CH);                // 590 KB
    size_t o_w1 = alloc((size_t)FC1_DIGITS * FC1_KB * FC1_OUT * 32);     // 51.4 MB
    size_t o_hp = alloc((size_t)FC1_DIGITS * TB * FC1_OUT * 4);          // 33.6 MB
    (void)ws_size;

    u8*     p1s    = (u8*)(ws + o_p1);
    u8*     z2     = (u8*)(ws + o_z);
    u8*     s3     = (u8*)(ws + o_s3);
    double* h4     = (double*)(ws + o_h4);
    s8*     Bt     = (s8*)(ws + o_wd);
    s8*     Wd1    = (s8*)(ws + o_w1);
    int*    Hpart  = (int*)(ws + o_hp);

    k2w_quant<<<dim3((CH * CH + 255) / 256), dim3(256), 0, stream>>>(w2, Bt);

    k4w_quant<<<dim3((FC1_KB * FC1_OUT + 255) / 256), dim3(256), 0, stream>>>(
        fw1, Wd1);

    k1_conv1_if_pool<<<dim3(512), dim3(256), 0, stream>>>(
        x, w1, g1, b1, m1, v1, p1s);

    k2_conv2_if_pool<<<dim3(512), dim3(448), 0, stream>>>(
        p1s, Bt, g2, b2, m2, v2, z2);

    k4_fc1_i8<<<dim3(256), dim3(512), 0, stream>>>(z2, Wd1, Hpart);

    k5_if3<<<dim3(BATCH * FC1_OUT / 256), dim3(256), 0, stream>>>(Hpart, s3);

    k6_fc2<<<dim3(TB), dim3(256), 0, stream>>>(s3, fw2, h4);

    k7_if4_mean<<<dim3((BATCH * FC2_OUT + 255) / 256), dim3(256), 0, stream>>>(h4, out);
}